// Round 15
// baseline (141.728 us; speedup 1.0000x reference)
//
#include <hip/hip_runtime.h>

typedef unsigned short u16;
typedef unsigned int u32;
typedef __bf16 bf16_t;
typedef bf16_t bf16x8 __attribute__((ext_vector_type(8)));
typedef float f32x4 __attribute__((ext_vector_type(4)));
typedef u32 u32x4 __attribute__((ext_vector_type(4)));

#define BATCH 8
#define CH 128
#define NSP 4096  // 64*64 spatial
#define LOG2E 1.44269504088896f

static __device__ __forceinline__ u16 f2bf(float f) {
  u32 u = __builtin_bit_cast(u32, f);
  u32 r = u + 0x7FFFu + ((u >> 16) & 1u);  // RNE
  return (u16)(r >> 16);
}

static __device__ __forceinline__ bf16x8 ld_bf8(const u16* p) {
  return __builtin_bit_cast(bf16x8, *(const u32x4*)p);
}

static __device__ __forceinline__ f32x4 mfma16(bf16x8 a, bf16x8 b, f32x4 c) {
  return __builtin_amdgcn_mfma_f32_16x16x32_bf16(a, b, c, 0, 0, 0);
}

static __device__ __forceinline__ u32 cvt_pk(float lo, float hi) {
  u32 r;
  asm("v_cvt_pk_bf16_f32 %0, %1, %2" : "=v"(r) : "v"(lo), "v"(hi));
  return r;
}

static __device__ __forceinline__ float fast_exp2(float x) {
#if __has_builtin(__builtin_amdgcn_exp2f)
  return __builtin_amdgcn_exp2f(x);
#else
  return exp2f(x);
#endif
}

static __device__ __forceinline__ void gl2lds16(const u16* g, u16* l) {
  __builtin_amdgcn_global_load_lds((const __attribute__((address_space(1))) void*)g,
                                   (__attribute__((address_space(3))) void*)l, 16, 0, 0);
}

// ---------------- GroupNorm stats (+ fused weight fp32->bf16 convert) ----------------
__global__ __launch_bounds__(256) void gn_stats_kernel(const float* __restrict__ x,
                                                       float* __restrict__ stats,
                                                       const float* __restrict__ wq,
                                                       const float* __restrict__ wk,
                                                       const float* __restrict__ wv,
                                                       const float* __restrict__ wo,
                                                       u16* __restrict__ wbf) {
  int bg = blockIdx.x;  // 0..255
  {
    int widx = bg * 256 + threadIdx.x;
    int m = widx >> 14, r = widx & 16383;
    const float* s = (m == 0) ? wq : (m == 1) ? wk : (m == 2) ? wv : wo;
    wbf[widx] = f2bf(s[r]);
  }
  const float4* p = (const float4*)(x + (size_t)bg * 16384);
  float s = 0.f, ss = 0.f;
  for (int i = threadIdx.x; i < 4096; i += 256) {
    float4 v = p[i];
    s += v.x + v.y + v.z + v.w;
    ss += v.x * v.x + v.y * v.y + v.z * v.z + v.w * v.w;
  }
  for (int off = 32; off; off >>= 1) {
    s += __shfl_xor(s, off);
    ss += __shfl_xor(ss, off);
  }
  __shared__ float rs[4], rss[4];
  int wave = threadIdx.x >> 6;
  if ((threadIdx.x & 63) == 0) { rs[wave] = s; rss[wave] = ss; }
  __syncthreads();
  if (threadIdx.x == 0) {
    s = rs[0] + rs[1] + rs[2] + rs[3];
    ss = rss[0] + rss[1] + rss[2] + rss[3];
    float mean = s * (1.f / 16384.f);
    float var = ss * (1.f / 16384.f) - mean * mean;
    stats[2 * bg] = mean;
    stats[2 * bg + 1] = rsqrtf(var + 1e-5f);
  }
}

// ---------------- fused GN-apply + QKV projections ----------------
// Reads x (b,c,n) directly, applies GN, transposes via f32 LDS tile, then 3 GEMMs.
// q: (b,n,c) bf16, pre-scaled by log2e/sqrt(C).
// k: (b,n,c') bf16 with slot permutation c' = ((c>>3) ^ (n&7))*8 + (c&7):
//    linear gl2lds staging + conflict-free fragment reads (r12-verified).
// v: (b,c,j') bf16 in PV-fragment order: fragment fr = kk2*4+lg at slot fr^(c&7);
//    element e of key jj: kk2 = jj>>5, lg = (jj&15)>>2, e = (jj&3)+(jj&16?4:0).
__global__ __launch_bounds__(256) void qkv_kernel(const float* __restrict__ x,
                                                  const float* __restrict__ stats,
                                                  const float* __restrict__ gnw,
                                                  const float* __restrict__ gnb,
                                                  const u16* __restrict__ wqb,
                                                  const u16* __restrict__ wkb,
                                                  const u16* __restrict__ wvb,
                                                  const float* __restrict__ bq,
                                                  const float* __restrict__ bk,
                                                  const float* __restrict__ bv,
                                                  u16* __restrict__ q, u16* __restrict__ k,
                                                  u16* __restrict__ v) {
  __shared__ float tile[64][132];  // x^T tile (n-local, c) f32; stride 132 keeps b128 reads clean
  __shared__ float sc[128], sh[128];
  int b = blockIdx.y;
  int n0 = blockIdx.x * 64;
  int t = threadIdx.x;
  if (t < 128) {
    float mean = stats[2 * (b * 32 + (t >> 2))];
    float rstd = stats[2 * (b * 32 + (t >> 2)) + 1];
    float w = gnw[t];
    sc[t] = rstd * w;
    sh[t] = gnb[t] - mean * rstd * w;
  }
  __syncthreads();
  const float4* xb4 = (const float4*)(x + (size_t)b * CH * NSP);
#pragma unroll
  for (int i = 0; i < 8; ++i) {
    int idx = t + i * 256;
    int c = idx >> 4, j4 = idx & 15;
    float4 vv = xb4[(size_t)c * (NSP / 4) + (n0 >> 2) + j4];
    float s_ = sc[c], h_ = sh[c];
    tile[j4 * 4 + 0][c] = vv.x * s_ + h_;
    tile[j4 * 4 + 1][c] = vv.y * s_ + h_;
    tile[j4 * 4 + 2][c] = vv.z * s_ + h_;
    tile[j4 * 4 + 3][c] = vv.w * s_ + h_;
  }
  __syncthreads();

  int wave = t >> 6, lane = t & 63;
  int lr = lane & 15, lg = lane >> 4;
  int n_base = n0 + wave * 16;
  int row = wave * 16 + lr;

  bf16x8 xfr[4];
#pragma unroll
  for (int kk = 0; kk < 4; ++kk) {
    const float* p = &tile[row][kk * 32 + lg * 8];
    f32x4 lo = *(const f32x4*)p;
    f32x4 hi = *(const f32x4*)(p + 4);
    u32x4 xw = {cvt_pk(lo[0], lo[1]), cvt_pk(lo[2], lo[3]),
                cvt_pk(hi[0], hi[1]), cvt_pk(hi[2], hi[3])};
    xfr[kk] = __builtin_bit_cast(bf16x8, xw);
  }

  f32x4 accq[8] = {}, acck[8] = {}, accv[8] = {};
#pragma unroll
  for (int kk = 0; kk < 4; ++kk) {
    int coff = kk * 32 + lg * 8;
    bf16x8 xa = xfr[kk];
#pragma unroll
    for (int ot = 0; ot < 8; ++ot) {
      int woff = (ot * 16 + lr) * CH + coff;
      bf16x8 wqf = ld_bf8(wqb + woff);
      bf16x8 wkf = ld_bf8(wkb + woff);
      bf16x8 wvf = ld_bf8(wvb + woff);
      accq[ot] = mfma16(xa, wqf, accq[ot]);
      acck[ot] = mfma16(xa, wkf, acck[ot]);
      accv[ot] = mfma16(wvf, xa, accv[ot]);
    }
  }
  const float qscale = 0.08838834764831845f * LOG2E;  // log2e/sqrt(128)
  // v-store fragment coords for this lane: key jj = wave*16 + lr within the tile
  int jj = wave * 16 + lr;
  int frv = (jj >> 5) * 4 + ((jj & 15) >> 2);  // kk2*4 + lg_v
  int ev = (lr & 3) + ((wave & 1) << 2);       // element within fragment
#pragma unroll
  for (int ot = 0; ot < 8; ++ot) {
    int o_col = ot * 16 + lr;
    float bqv = bq[o_col], bkv = bk[o_col];
#pragma unroll
    for (int r = 0; r < 4; ++r) {
      int nrow = n_base + lg * 4 + r;
      q[((size_t)b * NSP + nrow) * CH + o_col] = f2bf((accq[ot][r] + bqv) * qscale);
      int cperm = ((((o_col >> 3) ^ (nrow & 7)) << 3)) | (o_col & 7);
      k[((size_t)b * NSP + nrow) * CH + cperm] = f2bf(acck[ot][r] + bkv);
    }
#pragma unroll
    for (int r = 0; r < 4; ++r) {
      int c = ot * 16 + lg * 4 + r;  // v output channel
      int slot = frv ^ (c & 7);
      v[((size_t)(b * CH + c)) * NSP + blockIdx.x * 64 + slot * 8 + ev] =
          f2bf(accv[ot][r] + bv[c]);
    }
  }
}

// ---------------- flash attention (no-max, KV-split=3, 3 blocks/CU) ----------------
// 4 waves x 32 q-rows = 128 q-rows/block; KV tile 64; 21-22 iters/block; grid 768
// = 3 blocks/CU (b = id&7 -> XCD-local K/V). __launch_bounds__(256,3): register
// demand ~165 (qa32+s32+paw16+addr arch, oacc64 acc) fits the 170-reg cap because
// staging uses global_load_lds (NO staging registers; r12-verified permuted
// layouts -> linear LDS dest + conflict-free ds_reads).
// K double-buffered (STAGEK(t+1) issued at top, counted vmcnt(4) keeps it in
// flight across the barrier); V single-buffered (STAGEV(t+1) after the post-PV
// barrier; arrival guaranteed by next iter's vmcnt). LDS 48KB x 3 = 144 <= 160.
__global__ __launch_bounds__(256, 3) void attn_kernel(const u16* __restrict__ q,
                                                      const u16* __restrict__ k,
                                                      const u16* __restrict__ v,
                                                      u16* __restrict__ part0,
                                                      u16* __restrict__ part1,
                                                      u16* __restrict__ part2,
                                                      float* __restrict__ lbuf) {
  __shared__ __align__(16) u16 kbuf[2][64 * 128];  // 2 x 16 KB
  __shared__ __align__(16) u16 vbuf[128 * 64];     // 16 KB
  int id = blockIdx.x;
  int b = id & 7;
  int qblk = (id >> 3) & 31;
  int split = id >> 8;  // 0..2
  int wave = threadIdx.x >> 6, lane = threadIdx.x & 63;
  int lr = lane & 15, lg = lane >> 4;
  int i_base = qblk * 128 + wave * 32;
  int t0 = (split * 64) / 3;        // 0, 21, 42
  int t1 = ((split + 1) * 64) / 3;  // 21, 42, 64

  const u16* kg = k + (size_t)b * NSP * CH;
  const u16* vg = v + (size_t)b * CH * NSP;

  // Q fragments (B-operand: q-row at lane&15), 2 q-tiles x 4 k-chunks
  bf16x8 qa[2][4];
#pragma unroll
  for (int qt = 0; qt < 2; ++qt) {
    const u16* qrow = q + ((size_t)b * NSP + i_base + qt * 16 + lr) * CH;
#pragma unroll
    for (int kk = 0; kk < 4; ++kk) qa[qt][kk] = ld_bf8(qrow + kk * 32 + lg * 8);
  }
  asm volatile("s_waitcnt vmcnt(0)" ::: "memory");  // drain Q loads: clean vmcnt counting

  // staging (linear): K = 4 x 1024B (4 rows of 256B); V = 4 x 1024B (8 rows of 128B)
  auto STAGEK = [&](int t, int bi) {
    const u16* src = kg + ((size_t)(t * 64 + wave * 16)) * CH + lane * 8;
    u16* dst = &kbuf[bi][wave * 16 * 128];
#pragma unroll
    for (int g = 0; g < 4; ++g) gl2lds16(src + g * 512, dst + g * 512);
  };
  int vco = wave * 32 + (lane >> 3);
  auto STAGEV = [&](int t) {
    const u16* src = vg + t * 64 + (lane & 7) * 8;
    u16* dst = &vbuf[wave * 32 * 64];
#pragma unroll
    for (int g = 0; g < 4; ++g) gl2lds16(src + (size_t)(vco + g * 8) * NSP, dst + g * 512);
  };

  STAGEK(t0, 0);
  STAGEV(t0);

  f32x4 oacc[2][8] = {};
  float lsum[2] = {0.f, 0.f};

  for (int t = t0; t < t1; ++t) {
    int cur = (t - t0) & 1;
    const u16* kb = kbuf[cur];
    if (t + 1 < t1) {
      STAGEK(t + 1, cur ^ 1);  // K(t+1) into the other buffer; stays in flight
      asm volatile("s_waitcnt vmcnt(4)" ::: "memory");  // K(t),V(t) landed
    } else {
      asm volatile("s_waitcnt vmcnt(0)" ::: "memory");
    }
    __builtin_amdgcn_s_barrier();  // all waves' tile-t writes visible
    __builtin_amdgcn_sched_barrier(0);

    // ---- S^T = K Q^T : lane holds 16 scores for q-row lr (per qt) ----
    f32x4 s[2][4] = {};
    __builtin_amdgcn_s_setprio(1);
#pragma unroll
    for (int kk = 0; kk < 4; ++kk) {
#pragma unroll
      for (int jt = 0; jt < 4; ++jt) {
        int row = jt * 16 + lr;
        bf16x8 kf = ld_bf8(kb + row * 128 + ((((kk << 2) + lg) ^ (row & 7)) << 3));
        s[0][jt] = mfma16(kf, qa[0][kk], s[0][jt]);
        s[1][jt] = mfma16(kf, qa[1][kk], s[1][jt]);
      }
    }
    __builtin_amdgcn_s_setprio(0);

    // ---- P = exp2(S), in-lane l accumulation, pack to PV A-fragments ----
    u32x4 paw[2][2];
#pragma unroll
    for (int qt = 0; qt < 2; ++qt) {
      float sum = 0.f;
#pragma unroll
      for (int jt = 0; jt < 4; ++jt)
#pragma unroll
        for (int r = 0; r < 4; ++r) {
          float pv = fast_exp2(s[qt][jt][r]);
          s[qt][jt][r] = pv;
          sum += pv;
        }
      lsum[qt] += sum;
#pragma unroll
      for (int kk2 = 0; kk2 < 2; ++kk2) {
        paw[qt][kk2][0] = cvt_pk(s[qt][2 * kk2][0], s[qt][2 * kk2][1]);
        paw[qt][kk2][1] = cvt_pk(s[qt][2 * kk2][2], s[qt][2 * kk2][3]);
        paw[qt][kk2][2] = cvt_pk(s[qt][2 * kk2 + 1][0], s[qt][2 * kk2 + 1][1]);
        paw[qt][kk2][3] = cvt_pk(s[qt][2 * kk2 + 1][2], s[qt][2 * kk2 + 1][3]);
      }
    }

    // ---- O += P V (fragment chunk kk2; conflict-free swizzled reads) ----
    __builtin_amdgcn_s_setprio(1);
#pragma unroll
    for (int kk2 = 0; kk2 < 2; ++kk2) {
      bf16x8 pa0 = __builtin_bit_cast(bf16x8, paw[0][kk2]);
      bf16x8 pa1 = __builtin_bit_cast(bf16x8, paw[1][kk2]);
#pragma unroll
      for (int ct = 0; ct < 8; ++ct) {
        int c = ct * 16 + lr;
        bf16x8 vf = ld_bf8(vbuf + c * 64 + ((((kk2 << 2) + lg) ^ (c & 7)) << 3));
        oacc[0][ct] = mfma16(pa0, vf, oacc[0][ct]);
        oacc[1][ct] = mfma16(pa1, vf, oacc[1][ct]);
      }
    }
    __builtin_amdgcn_s_setprio(0);

    __builtin_amdgcn_s_barrier();       // all waves done with vbuf(t)
    if (t + 1 < t1) STAGEV(t + 1);      // V(t+1) into vbuf; waited next iter
  }

  // ---- epilogue: reduce l across lane groups; write unnormalized partial ----
  u16* pdst = (split == 0) ? part0 : (split == 1) ? part1 : part2;
  float* ldst = lbuf + (size_t)split * (BATCH * NSP) + (size_t)b * NSP;
#pragma unroll
  for (int qt = 0; qt < 2; ++qt) {
    lsum[qt] += __shfl_xor(lsum[qt], 16);
    lsum[qt] += __shfl_xor(lsum[qt], 32);
    if (lg == 0) ldst[i_base + qt * 16 + lr] = lsum[qt];
#pragma unroll
    for (int r = 0; r < 4; ++r) {
      int i = i_base + qt * 16 + lg * 4 + r;
      u16* row = pdst + ((size_t)b * NSP + i) * CH;
#pragma unroll
      for (int ct = 0; ct < 8; ++ct) row[ct * 16 + lr] = f2bf(oacc[qt][ct][r]);
    }
  }
}

// ---------------- combine three KV-split partials (serializes d_out scratch use) -----
__global__ __launch_bounds__(256) void combine_kernel(const u16* __restrict__ p0,
                                                      const u16* __restrict__ p1,
                                                      const u16* __restrict__ p2,
                                                      const float* __restrict__ lbuf,
                                                      u16* __restrict__ omid) {
  int idx = blockIdx.x * 256 + threadIdx.x;  // 0..524287
  int row = idx >> 4, coff = (idx & 15) * 8;
  const int BN = BATCH * NSP;
  float l = lbuf[row] + lbuf[BN + row] + lbuf[2 * BN + row];
  float inv = 1.f / l;
  bf16x8 a = ld_bf8(p0 + (size_t)row * CH + coff);
  bf16x8 bb = ld_bf8(p1 + (size_t)row * CH + coff);
  bf16x8 cc = ld_bf8(p2 + (size_t)row * CH + coff);
  u16 outv[8];
#pragma unroll
  for (int e = 0; e < 8; ++e)
    outv[e] = f2bf(((float)a[e] + (float)bb[e] + (float)cc[e]) * inv);
  *(u32x4*)(omid + (size_t)row * CH + coff) = *(const u32x4*)outv;
}

// ---------------- output projection + residual ----------------
__global__ __launch_bounds__(256) void proj_kernel(const u16* __restrict__ omid,
                                                   const u16* __restrict__ wob,
                                                   const float* __restrict__ bo,
                                                   const float* __restrict__ gamma,
                                                   const float* __restrict__ x,
                                                   float* __restrict__ out) {
  int b = blockIdx.y;
  int wave = threadIdx.x >> 6, lane = threadIdx.x & 63;
  int lr = lane & 15, lg = lane >> 4;
  int n_base = blockIdx.x * 64 + wave * 16;
  const u16* orow = omid + ((size_t)b * NSP + n_base + lr) * CH;
  f32x4 acc[8] = {};
#pragma unroll
  for (int kk = 0; kk < 4; ++kk) {
    int coff = kk * 32 + lg * 8;
    bf16x8 ofrag = ld_bf8(orow + coff);
#pragma unroll
    for (int ot = 0; ot < 8; ++ot) {
      bf16x8 wf = ld_bf8(wob + (ot * 16 + lr) * CH + coff);
      acc[ot] = mfma16(wf, ofrag, acc[ot]);
    }
  }
  float g = gamma[0];
  int n_col = n_base + lr;
#pragma unroll
  for (int ot = 0; ot < 8; ++ot) {
#pragma unroll
    for (int r = 0; r < 4; ++r) {
      int o_row = ot * 16 + lg * 4 + r;
      size_t off = ((size_t)b * CH + o_row) * NSP + n_col;
      out[off] = x[off] + g * (acc[ot][r] + bo[o_row]);
    }
  }
}

extern "C" void kernel_launch(void* const* d_in, const int* in_sizes, int n_in,
                              void* d_out, int out_size, void* d_ws, size_t ws_size,
                              hipStream_t stream) {
  const float* x = (const float*)d_in[0];
  const float* gnw = (const float*)d_in[1];
  const float* gnb = (const float*)d_in[2];
  const float* wq = (const float*)d_in[3];
  const float* bq = (const float*)d_in[4];
  const float* wk = (const float*)d_in[5];
  const float* bk = (const float*)d_in[6];
  const float* wv = (const float*)d_in[7];
  const float* bv = (const float*)d_in[8];
  const float* wo = (const float*)d_in[9];
  const float* bo = (const float*)d_in[10];
  const float* gamma = (const float*)d_in[11];
  float* out = (float*)d_out;

  const size_t BUF = (size_t)BATCH * NSP * CH * sizeof(u16);  // 8 MB
  char* ws = (char*)d_ws;
  u16* wbf = (u16*)ws;             // 4 x 128x128 bf16 = 128KB
  float* stats = (float*)(ws + 131072);
  u16* xd = (u16*)(ws + 262144);   // split0 partial O
  u16* qb = (u16*)(ws + 262144 + BUF);
  u16* kb = (u16*)(ws + 262144 + 2 * BUF);  // later: combined O_mid
  u16* vb = (u16*)(ws + 262144 + 3 * BUF);
  float* lbuf = (float*)(ws + 262144 + 4 * BUF);  // 3 x 32768 f32 = 384KB
  const size_t need = 262144 + 4 * BUF + 393216;
  if (ws_size < need) return;
  // part1: prefer extra ws; else reuse qb (Q read only in attn prologue; grid=768 at
  // 3 blocks/CU is fully co-resident -> epilogue writes land long after all Q reads)
  u16* part1 = (ws_size >= need + BUF) ? (u16*)(ws + need) : qb;
  // part2 lives in d_out (16 MB f32 output holds one 8 MB bf16 partial);
  // combine_kernel consumes it BEFORE proj_kernel writes d_out (stream-serialized).
  u16* part2 = (u16*)d_out;

  gn_stats_kernel<<<256, 256, 0, stream>>>(x, stats, wq, wk, wv, wo, wbf);
  qkv_kernel<<<dim3(64, 8), 256, 0, stream>>>(x, stats, gnw, gnb, wbf, wbf + 16384,
                                              wbf + 32768, bq, bk, bv, qb, kb, vb);
  attn_kernel<<<768, 256, 0, stream>>>(qb, kb, vb, xd, part1, part2, lbuf);
  combine_kernel<<<2048, 256, 0, stream>>>(xd, part1, part2, lbuf, kb);
  proj_kernel<<<dim3(64, 8), 256, 0, stream>>>(kb, wbf + 49152, bo, gamma, x, out);
}

// Round 16
// 135.581 us; speedup vs baseline: 1.0453x; 1.0453x over previous
//
#include <hip/hip_runtime.h>

typedef unsigned short u16;
typedef unsigned int u32;
typedef __bf16 bf16_t;
typedef bf16_t bf16x8 __attribute__((ext_vector_type(8)));
typedef float f32x4 __attribute__((ext_vector_type(4)));
typedef u32 u32x4 __attribute__((ext_vector_type(4)));
typedef u32 u32x2 __attribute__((ext_vector_type(2)));

#define BATCH 8
#define CH 128
#define NSP 4096  // 64*64 spatial
#define LOG2E 1.44269504088896f

static __device__ __forceinline__ u16 f2bf(float f) {
  u32 u = __builtin_bit_cast(u32, f);
  u32 r = u + 0x7FFFu + ((u >> 16) & 1u);  // RNE
  return (u16)(r >> 16);
}

static __device__ __forceinline__ bf16x8 ld_bf8(const u16* p) {
  return __builtin_bit_cast(bf16x8, *(const u32x4*)p);
}

static __device__ __forceinline__ f32x4 mfma16(bf16x8 a, bf16x8 b, f32x4 c) {
  return __builtin_amdgcn_mfma_f32_16x16x32_bf16(a, b, c, 0, 0, 0);
}

static __device__ __forceinline__ u32 cvt_pk(float lo, float hi) {
  u32 r;
  asm("v_cvt_pk_bf16_f32 %0, %1, %2" : "=v"(r) : "v"(lo), "v"(hi));
  return r;
}

static __device__ __forceinline__ float fast_exp2(float x) {
#if __has_builtin(__builtin_amdgcn_exp2f)
  return __builtin_amdgcn_exp2f(x);
#else
  return exp2f(x);
#endif
}

// ---------------- GroupNorm stats (+ fused weight fp32->bf16 convert) ----------------
__global__ __launch_bounds__(256) void gn_stats_kernel(const float* __restrict__ x,
                                                       float* __restrict__ stats,
                                                       const float* __restrict__ wq,
                                                       const float* __restrict__ wk,
                                                       const float* __restrict__ wv,
                                                       const float* __restrict__ wo,
                                                       u16* __restrict__ wbf) {
  int bg = blockIdx.x;  // 0..255
  {
    int widx = bg * 256 + threadIdx.x;
    int m = widx >> 14, r = widx & 16383;
    const float* s = (m == 0) ? wq : (m == 1) ? wk : (m == 2) ? wv : wo;
    wbf[widx] = f2bf(s[r]);
  }
  const float4* p = (const float4*)(x + (size_t)bg * 16384);
  float s = 0.f, ss = 0.f;
  for (int i = threadIdx.x; i < 4096; i += 256) {
    float4 v = p[i];
    s += v.x + v.y + v.z + v.w;
    ss += v.x * v.x + v.y * v.y + v.z * v.z + v.w * v.w;
  }
  for (int off = 32; off; off >>= 1) {
    s += __shfl_xor(s, off);
    ss += __shfl_xor(ss, off);
  }
  __shared__ float rs[4], rss[4];
  int wave = threadIdx.x >> 6;
  if ((threadIdx.x & 63) == 0) { rs[wave] = s; rss[wave] = ss; }
  __syncthreads();
  if (threadIdx.x == 0) {
    s = rs[0] + rs[1] + rs[2] + rs[3];
    ss = rss[0] + rss[1] + rss[2] + rss[3];
    float mean = s * (1.f / 16384.f);
    float var = ss * (1.f / 16384.f) - mean * mean;
    stats[2 * bg] = mean;
    stats[2 * bg + 1] = rsqrtf(var + 1e-5f);
  }
}

// ---------------- fused GN-apply + QKV projections ----------------
// Reads x (b,c,n) directly, applies GN, transposes via f32 LDS tile, then the 3
// GEMMs. q,k: (b,n,c) bf16 (q pre-scaled by log2e/sqrt(C)); v: (b,c,n) bf16.
__global__ __launch_bounds__(256) void qkv_kernel(const float* __restrict__ x,
                                                  const float* __restrict__ stats,
                                                  const float* __restrict__ gnw,
                                                  const float* __restrict__ gnb,
                                                  const u16* __restrict__ wqb,
                                                  const u16* __restrict__ wkb,
                                                  const u16* __restrict__ wvb,
                                                  const float* __restrict__ bq,
                                                  const float* __restrict__ bk,
                                                  const float* __restrict__ bv,
                                                  u16* __restrict__ q, u16* __restrict__ k,
                                                  u16* __restrict__ v) {
  __shared__ float tile[64][132];  // x^T tile (n-local, c) f32; stride 132 keeps b128 reads clean
  __shared__ float sc[128], sh[128];
  int b = blockIdx.y;
  int n0 = blockIdx.x * 64;
  int t = threadIdx.x;
  if (t < 128) {
    float mean = stats[2 * (b * 32 + (t >> 2))];
    float rstd = stats[2 * (b * 32 + (t >> 2)) + 1];
    float w = gnw[t];
    sc[t] = rstd * w;
    sh[t] = gnb[t] - mean * rstd * w;
  }
  __syncthreads();
  const float4* xb4 = (const float4*)(x + (size_t)b * CH * NSP);
#pragma unroll
  for (int i = 0; i < 8; ++i) {
    int idx = t + i * 256;
    int c = idx >> 4, j4 = idx & 15;
    float4 vv = xb4[(size_t)c * (NSP / 4) + (n0 >> 2) + j4];
    float s_ = sc[c], h_ = sh[c];
    tile[j4 * 4 + 0][c] = vv.x * s_ + h_;
    tile[j4 * 4 + 1][c] = vv.y * s_ + h_;
    tile[j4 * 4 + 2][c] = vv.z * s_ + h_;
    tile[j4 * 4 + 3][c] = vv.w * s_ + h_;
  }
  __syncthreads();

  int wave = t >> 6, lane = t & 63;
  int lr = lane & 15, lg = lane >> 4;
  int n_base = n0 + wave * 16;
  int row = wave * 16 + lr;

  bf16x8 xfr[4];
#pragma unroll
  for (int kk = 0; kk < 4; ++kk) {
    const float* p = &tile[row][kk * 32 + lg * 8];
    f32x4 lo = *(const f32x4*)p;
    f32x4 hi = *(const f32x4*)(p + 4);
    u32x4 xw = {cvt_pk(lo[0], lo[1]), cvt_pk(lo[2], lo[3]),
                cvt_pk(hi[0], hi[1]), cvt_pk(hi[2], hi[3])};
    xfr[kk] = __builtin_bit_cast(bf16x8, xw);
  }

  f32x4 accq[8] = {}, acck[8] = {}, accv[8] = {};
#pragma unroll
  for (int kk = 0; kk < 4; ++kk) {
    int coff = kk * 32 + lg * 8;
    bf16x8 xa = xfr[kk];
#pragma unroll
    for (int ot = 0; ot < 8; ++ot) {
      int woff = (ot * 16 + lr) * CH + coff;
      bf16x8 wqf = ld_bf8(wqb + woff);
      bf16x8 wkf = ld_bf8(wkb + woff);
      bf16x8 wvf = ld_bf8(wvb + woff);
      accq[ot] = mfma16(xa, wqf, accq[ot]);
      acck[ot] = mfma16(xa, wkf, acck[ot]);
      accv[ot] = mfma16(wvf, xa, accv[ot]);
    }
  }
  const float qscale = 0.08838834764831845f * LOG2E;  // log2e/sqrt(128)
#pragma unroll
  for (int ot = 0; ot < 8; ++ot) {
    int o_col = ot * 16 + lr;
    float bqv = bq[o_col], bkv = bk[o_col];
#pragma unroll
    for (int r = 0; r < 4; ++r) {
      int nrow = n_base + lg * 4 + r;
      size_t off = ((size_t)b * NSP + nrow) * CH + o_col;
      q[off] = f2bf((accq[ot][r] + bqv) * qscale);
      k[off] = f2bf(acck[ot][r] + bkv);
    }
    int n_col = n_base + lr;
#pragma unroll
    for (int r = 0; r < 4; ++r) {
      int o_row = ot * 16 + lg * 4 + r;
      v[((size_t)b * CH + o_row) * NSP + n_col] = f2bf(accv[ot][r] + bv[o_row]);
    }
  }
}

// ---------------- flash attention (no-max, KV-split=2, reg-staged, LDS double-buffer) -
// r14 structure (84.7us verified best) with ONE change: softmax and PV are
// interleaved per key-half kk2 — pack(kk2=0) -> PV(kk2=0) -> pack(kk2=1) ->
// PV(kk2=1). The 32 exp2+cvt_pk of kk2=1 are independent of PV(kk2=0)'s MFMAs,
// so trans/VALU overlaps the MFMA pipe within the wave; paw liveness halves.
// V-fragment reads unchanged (16/iter, each feeds both qt). lsum: pairwise tree.
#define KSTRIDE 136  // 128 + 8 u16 pad
#define VSTRIDE 72   // 64 + 8 u16 pad
__global__ __launch_bounds__(256, 2) void attn_kernel(const u16* __restrict__ q,
                                                      const u16* __restrict__ k,
                                                      const u16* __restrict__ v,
                                                      u16* __restrict__ part0,
                                                      u16* __restrict__ part1,
                                                      float* __restrict__ lbuf) {
  __shared__ __align__(16) u16 kbuf[2][64 * KSTRIDE];  // 2 x 17408 B
  __shared__ __align__(16) u16 vbuf[2][128 * VSTRIDE]; // 2 x 18432 B
  int id = blockIdx.x;
  int b = id & 7;
  int qblk = (id >> 3) & 31;
  int split = id >> 8;  // 0 or 1
  int wave = threadIdx.x >> 6, lane = threadIdx.x & 63;
  int lr = lane & 15, lg = lane >> 4;
  int i_base = qblk * 128 + wave * 32;
  int t0 = split * 32, t1 = t0 + 32;

  const u16* kg = k + (size_t)b * NSP * CH;
  const u16* vg = v + (size_t)b * CH * NSP;

  // Q fragments (B-operand: q-row at lane&15), 2 q-tiles x 4 k-chunks
  bf16x8 qa[2][4];
#pragma unroll
  for (int qt = 0; qt < 2; ++qt) {
    const u16* qrow = q + ((size_t)b * NSP + i_base + qt * 16 + lr) * CH;
#pragma unroll
    for (int kk = 0; kk < 4; ++kk) qa[qt][kk] = ld_bf8(qrow + kk * 32 + lg * 8);
  }

  // ---- K staging: instr m covers rows wave*16 + m*4 + (lane>>4), chunk lane&15 ----
  int kgo[4], klo[4];
#pragma unroll
  for (int m = 0; m < 4; ++m) {
    int kr = wave * 16 + m * 4 + (lane >> 4);
    kgo[m] = kr * CH + (lane & 15) * 8;       // global (u16), + t*64*CH per tile
    klo[m] = kr * KSTRIDE + (lane & 15) * 8;  // LDS (u16)
  }
  // ---- V staging: instr w covers rows c = wave*32 + w*8 + (lane>>3), chunk f=lane&7.
  // LDS chunk f holds granules {p, p+4}, p = (f>>2)*8 + (f&3)  (granule = 4 u16).
  int vgo[4][2], vlo[4];
  {
    int f = lane & 7;
    int p = ((lane >> 2) & 1) * 8 + (lane & 3);
#pragma unroll
    for (int w = 0; w < 4; ++w) {
      int c = wave * 32 + w * 8 + (lane >> 3);
      vgo[w][0] = c * NSP + p * 4;        // + t*64 per tile
      vgo[w][1] = c * NSP + (p + 4) * 4;
      vlo[w] = c * VSTRIDE + f * 8;
    }
  }

  u32x4 kstg[4];
  u32x2 vstg[4][2];
  auto KLOAD = [&](int t) {
    const u16* kt = kg + (size_t)t * (64 * CH);
#pragma unroll
    for (int m = 0; m < 4; ++m) kstg[m] = *(const u32x4*)(kt + kgo[m]);
  };
  auto VLOAD = [&](int t) {
    const u16* vt = vg + t * 64;
#pragma unroll
    for (int w = 0; w < 4; ++w) {
      vstg[w][0] = *(const u32x2*)(vt + vgo[w][0]);
      vstg[w][1] = *(const u32x2*)(vt + vgo[w][1]);
    }
  };
  auto KVWRITE = [&](int bi) {
    u16* kb2 = kbuf[bi];
    u16* vb2 = vbuf[bi];
#pragma unroll
    for (int m = 0; m < 4; ++m) *(u32x4*)(kb2 + klo[m]) = kstg[m];
#pragma unroll
    for (int w = 0; w < 4; ++w) {
      u32x4 d = {vstg[w][0][0], vstg[w][0][1], vstg[w][1][0], vstg[w][1][1]};
      *(u32x4*)(vb2 + vlo[w]) = d;
    }
  };

  // prologue: tile t0 into buf0; t0+1 loads in flight
  KLOAD(t0);
  VLOAD(t0);
  asm volatile("s_waitcnt vmcnt(0)" ::: "memory");
  KVWRITE(0);
  KLOAD(t0 + 1);
  VLOAD(t0 + 1);
  asm volatile("s_waitcnt lgkmcnt(0)" ::: "memory");
  __builtin_amdgcn_s_barrier();
  __builtin_amdgcn_sched_barrier(0);

  f32x4 oacc[2][8] = {};
  float lsum[2] = {0.f, 0.f};

  for (int t = t0; t < t1; ++t) {
    int cur = (t - t0) & 1;
    const u16* kb = kbuf[cur];
    const u16* vb = vbuf[cur];

    // ---- S^T = K Q^T : lane holds 16 scores for q-row lr (per qt) ----
    f32x4 s[2][4] = {};
    __builtin_amdgcn_s_setprio(1);
#pragma unroll
    for (int kk = 0; kk < 4; ++kk) {
#pragma unroll
      for (int jt = 0; jt < 4; ++jt) {
        int row = jt * 16 + lr;
        bf16x8 kf = ld_bf8(kb + row * KSTRIDE + (kk * 4 + lg) * 8);
        s[0][jt] = mfma16(kf, qa[0][kk], s[0][jt]);
        s[1][jt] = mfma16(kf, qa[1][kk], s[1][jt]);
      }
    }
    __builtin_amdgcn_s_setprio(0);

    // ---- softmax+PV interleaved per key-half: pack(kk2) then PV(kk2).
    //      exp2/cvt_pk of kk2=1 overlap PV(kk2=0)'s MFMAs (independent). ----
#pragma unroll
    for (int kk2 = 0; kk2 < 2; ++kk2) {
      u32x4 paw[2];
#pragma unroll
      for (int qt = 0; qt < 2; ++qt) {
        float p0 = fast_exp2(s[qt][2 * kk2][0]);
        float p1 = fast_exp2(s[qt][2 * kk2][1]);
        float p2 = fast_exp2(s[qt][2 * kk2][2]);
        float p3 = fast_exp2(s[qt][2 * kk2][3]);
        float p4 = fast_exp2(s[qt][2 * kk2 + 1][0]);
        float p5 = fast_exp2(s[qt][2 * kk2 + 1][1]);
        float p6 = fast_exp2(s[qt][2 * kk2 + 1][2]);
        float p7 = fast_exp2(s[qt][2 * kk2 + 1][3]);
        lsum[qt] += ((p0 + p1) + (p2 + p3)) + ((p4 + p5) + (p6 + p7));
        paw[qt][0] = cvt_pk(p0, p1);
        paw[qt][1] = cvt_pk(p2, p3);
        paw[qt][2] = cvt_pk(p4, p5);
        paw[qt][3] = cvt_pk(p6, p7);
      }
      bf16x8 pa0 = __builtin_bit_cast(bf16x8, paw[0]);
      bf16x8 pa1 = __builtin_bit_cast(bf16x8, paw[1]);
      __builtin_amdgcn_s_setprio(1);
#pragma unroll
      for (int ct = 0; ct < 8; ++ct) {
        int c = ct * 16 + lr;
        bf16x8 vf = ld_bf8(vb + c * VSTRIDE + (kk2 * 4 + lg) * 8);
        oacc[0][ct] = mfma16(pa0, vf, oacc[0][ct]);
        oacc[1][ct] = mfma16(pa1, vf, oacc[1][ct]);
      }
      __builtin_amdgcn_s_setprio(0);
    }

    if (t + 1 < t1) {
      asm volatile("s_waitcnt vmcnt(0)" ::: "memory");  // regs for t+1 arrived
      KVWRITE(cur ^ 1);                                 // write tile t+1 (other buffer)
      if (t + 2 < t1) {  // fire-and-forget: a full compute phase to land
        KLOAD(t + 2);
        VLOAD(t + 2);
      }
      asm volatile("s_waitcnt lgkmcnt(0)" ::: "memory");  // my ds_writes drained
      __builtin_amdgcn_s_barrier();                       // tile t+1 visible to all
      __builtin_amdgcn_sched_barrier(0);
    }
  }

  // ---- epilogue: reduce l across lane groups; write unnormalized partial ----
  u16* pdst = (split == 0) ? part0 : part1;
  float* ldst = lbuf + (size_t)split * (BATCH * NSP) + (size_t)b * NSP;
#pragma unroll
  for (int qt = 0; qt < 2; ++qt) {
    lsum[qt] += __shfl_xor(lsum[qt], 16);
    lsum[qt] += __shfl_xor(lsum[qt], 32);
    if (lg == 0) ldst[i_base + qt * 16 + lr] = lsum[qt];
#pragma unroll
    for (int r = 0; r < 4; ++r) {
      int i = i_base + qt * 16 + lg * 4 + r;
      u16* row = pdst + ((size_t)b * NSP + i) * CH;
#pragma unroll
      for (int ct = 0; ct < 8; ++ct) row[ct * 16 + lr] = f2bf(oacc[qt][ct][r]);
    }
  }
}

// ---------------- output projection + residual (combines the 2 KV-split partials) ----
__global__ __launch_bounds__(256) void proj_kernel(const u16* __restrict__ p0,
                                                   const u16* __restrict__ p1,
                                                   const float* __restrict__ lbuf,
                                                   const u16* __restrict__ wob,
                                                   const float* __restrict__ bo,
                                                   const float* __restrict__ gamma,
                                                   const float* __restrict__ x,
                                                   float* __restrict__ out) {
  int b = blockIdx.y;
  int wave = threadIdx.x >> 6, lane = threadIdx.x & 63;
  int lr = lane & 15, lg = lane >> 4;
  int n_base = blockIdx.x * 64 + wave * 16;
  int nrow = n_base + lr;
  float linv = 1.f / (lbuf[(size_t)b * NSP + nrow] +
                      lbuf[(size_t)BATCH * NSP + (size_t)b * NSP + nrow]);
  const u16* r0 = p0 + ((size_t)b * NSP + nrow) * CH;
  const u16* r1 = p1 + ((size_t)b * NSP + nrow) * CH;
  f32x4 acc[8] = {};
#pragma unroll
  for (int kk = 0; kk < 4; ++kk) {
    int coff = kk * 32 + lg * 8;
    bf16x8 a = ld_bf8(r0 + coff);
    bf16x8 bb = ld_bf8(r1 + coff);
    u32 w0 = cvt_pk(((float)a[0] + (float)bb[0]) * linv, ((float)a[1] + (float)bb[1]) * linv);
    u32 w1 = cvt_pk(((float)a[2] + (float)bb[2]) * linv, ((float)a[3] + (float)bb[3]) * linv);
    u32 w2 = cvt_pk(((float)a[4] + (float)bb[4]) * linv, ((float)a[5] + (float)bb[5]) * linv);
    u32 w3 = cvt_pk(((float)a[6] + (float)bb[6]) * linv, ((float)a[7] + (float)bb[7]) * linv);
    u32x4 wv = {w0, w1, w2, w3};
    bf16x8 ofrag = __builtin_bit_cast(bf16x8, wv);
#pragma unroll
    for (int ot = 0; ot < 8; ++ot) {
      bf16x8 wf = ld_bf8(wob + (ot * 16 + lr) * CH + coff);
      acc[ot] = mfma16(wf, ofrag, acc[ot]);
    }
  }
  float g = gamma[0];
  int n_col = n_base + lr;
#pragma unroll
  for (int ot = 0; ot < 8; ++ot) {
#pragma unroll
    for (int r = 0; r < 4; ++r) {
      int o_row = ot * 16 + lg * 4 + r;
      size_t off = ((size_t)b * CH + o_row) * NSP + n_col;
      out[off] = x[off] + g * (acc[ot][r] + bo[o_row]);
    }
  }
}

extern "C" void kernel_launch(void* const* d_in, const int* in_sizes, int n_in,
                              void* d_out, int out_size, void* d_ws, size_t ws_size,
                              hipStream_t stream) {
  const float* x = (const float*)d_in[0];
  const float* gnw = (const float*)d_in[1];
  const float* gnb = (const float*)d_in[2];
  const float* wq = (const float*)d_in[3];
  const float* bq = (const float*)d_in[4];
  const float* wk = (const float*)d_in[5];
  const float* bk = (const float*)d_in[6];
  const float* wv = (const float*)d_in[7];
  const float* bv = (const float*)d_in[8];
  const float* wo = (const float*)d_in[9];
  const float* bo = (const float*)d_in[10];
  const float* gamma = (const float*)d_in[11];
  float* out = (float*)d_out;

  const size_t BUF = (size_t)BATCH * NSP * CH * sizeof(u16);  // 8 MB
  char* ws = (char*)d_ws;
  u16* wbf = (u16*)ws;             // 4 x 128x128 bf16 = 128KB
  float* stats = (float*)(ws + 131072);
  u16* xd = (u16*)(ws + 262144);   // split0 partial O
  u16* qb = (u16*)(ws + 262144 + BUF);
  u16* kb = (u16*)(ws + 262144 + 2 * BUF);
  u16* vb = (u16*)(ws + 262144 + 3 * BUF);
  float* lbuf = (float*)(ws + 262144 + 4 * BUF);  // 2 x 32768 f32 = 256KB
  const size_t need = 262144 + 4 * BUF + 262144;
  if (ws_size < need) return;
  // split1 partial: prefer extra ws space; else reuse qb (Q read only in attn prologue;
  // grid=512 at 2 blocks/CU is fully co-resident, epilogue writes land long after reads)
  u16* part1 = (ws_size >= need + BUF) ? (u16*)(ws + need) : qb;

  gn_stats_kernel<<<256, 256, 0, stream>>>(x, stats, wq, wk, wv, wo, wbf);
  qkv_kernel<<<dim3(64, 8), 256, 0, stream>>>(x, stats, gnw, gnb, wbf, wbf + 16384,
                                              wbf + 32768, bq, bk, bv, qb, kb, vb);
  attn_kernel<<<512, 256, 0, stream>>>(qb, kb, vb, xd, part1, lbuf);
  proj_kernel<<<dim3(64, 8), 256, 0, stream>>>(xd, part1, lbuf, wbf + 49152, bo, gamma,
                                               x, out);
}

// Round 17
// 127.361 us; speedup vs baseline: 1.1128x; 1.0645x over previous
//
#include <hip/hip_runtime.h>

typedef unsigned short u16;
typedef unsigned int u32;
typedef __bf16 bf16_t;
typedef bf16_t bf16x8 __attribute__((ext_vector_type(8)));
typedef float f32x4 __attribute__((ext_vector_type(4)));
typedef u32 u32x4 __attribute__((ext_vector_type(4)));

#define BATCH 8
#define CH 128
#define NSP 4096  // 64*64 spatial
#define LOG2E 1.44269504088896f

static __device__ __forceinline__ u16 f2bf(float f) {
  u32 u = __builtin_bit_cast(u32, f);
  u32 r = u + 0x7FFFu + ((u >> 16) & 1u);  // RNE
  return (u16)(r >> 16);
}

static __device__ __forceinline__ bf16x8 ld_bf8(const u16* p) {
  return __builtin_bit_cast(bf16x8, *(const u32x4*)p);
}

static __device__ __forceinline__ f32x4 mfma16(bf16x8 a, bf16x8 b, f32x4 c) {
  return __builtin_amdgcn_mfma_f32_16x16x32_bf16(a, b, c, 0, 0, 0);
}

static __device__ __forceinline__ u32 cvt_pk(float lo, float hi) {
  u32 r;
  asm("v_cvt_pk_bf16_f32 %0, %1, %2" : "=v"(r) : "v"(lo), "v"(hi));
  return r;
}

static __device__ __forceinline__ float fast_exp2(float x) {
#if __has_builtin(__builtin_amdgcn_exp2f)
  return __builtin_amdgcn_exp2f(x);
#else
  return exp2f(x);
#endif
}

static __device__ __forceinline__ void gl2lds16(const u16* g, u16* l) {
  __builtin_amdgcn_global_load_lds((const __attribute__((address_space(1))) void*)g,
                                   (__attribute__((address_space(3))) void*)l, 16, 0, 0);
}

// ---------------- GroupNorm stats (+ fused weight fp32->bf16 convert) ----------------
__global__ __launch_bounds__(256) void gn_stats_kernel(const float* __restrict__ x,
                                                       float* __restrict__ stats,
                                                       const float* __restrict__ wq,
                                                       const float* __restrict__ wk,
                                                       const float* __restrict__ wv,
                                                       const float* __restrict__ wo,
                                                       u16* __restrict__ wbf) {
  int bg = blockIdx.x;  // 0..255
  {
    int widx = bg * 256 + threadIdx.x;
    int m = widx >> 14, r = widx & 16383;
    const float* s = (m == 0) ? wq : (m == 1) ? wk : (m == 2) ? wv : wo;
    wbf[widx] = f2bf(s[r]);
  }
  const float4* p = (const float4*)(x + (size_t)bg * 16384);
  float s = 0.f, ss = 0.f;
  for (int i = threadIdx.x; i < 4096; i += 256) {
    float4 v = p[i];
    s += v.x + v.y + v.z + v.w;
    ss += v.x * v.x + v.y * v.y + v.z * v.z + v.w * v.w;
  }
  for (int off = 32; off; off >>= 1) {
    s += __shfl_xor(s, off);
    ss += __shfl_xor(ss, off);
  }
  __shared__ float rs[4], rss[4];
  int wave = threadIdx.x >> 6;
  if ((threadIdx.x & 63) == 0) { rs[wave] = s; rss[wave] = ss; }
  __syncthreads();
  if (threadIdx.x == 0) {
    s = rs[0] + rs[1] + rs[2] + rs[3];
    ss = rss[0] + rss[1] + rss[2] + rss[3];
    float mean = s * (1.f / 16384.f);
    float var = ss * (1.f / 16384.f) - mean * mean;
    stats[2 * bg] = mean;
    stats[2 * bg + 1] = rsqrtf(var + 1e-5f);
  }
}

// ---------------- fused GN-apply + QKV projections (permuted K/V outputs) ----------------
// Reads x (b,c,n) directly, applies GN, transposes via f32 LDS tile, then 3 GEMMs.
// q: (b,n,c) bf16, pre-scaled by log2e/sqrt(C).
// k: (b,n,c') bf16, c' = ((c>>3) ^ (n&7))*8 + (c&7): linear gl2lds staging then
//    reading fragment (kk,lg) at slot (kk*4+lg)^(n&7) is correct + conflict-free.
// v: (b,c,j') bf16 in PV-fragment order: fragment fr = kk2*4+lg at slot fr^(c&7);
//    element e of key jj: kk2 = jj>>5, lg = (jj&15)>>2, e = (jj&3)+(jj&16?4:0).
// (All three layouts verified passing in rounds 12 and 15.)
__global__ __launch_bounds__(256) void qkv_kernel(const float* __restrict__ x,
                                                  const float* __restrict__ stats,
                                                  const float* __restrict__ gnw,
                                                  const float* __restrict__ gnb,
                                                  const u16* __restrict__ wqb,
                                                  const u16* __restrict__ wkb,
                                                  const u16* __restrict__ wvb,
                                                  const float* __restrict__ bq,
                                                  const float* __restrict__ bk,
                                                  const float* __restrict__ bv,
                                                  u16* __restrict__ q, u16* __restrict__ k,
                                                  u16* __restrict__ v) {
  __shared__ float tile[64][132];  // x^T tile (n-local, c) f32; stride 132 keeps b128 reads clean
  __shared__ float sc[128], sh[128];
  int b = blockIdx.y;
  int n0 = blockIdx.x * 64;
  int t = threadIdx.x;
  if (t < 128) {
    float mean = stats[2 * (b * 32 + (t >> 2))];
    float rstd = stats[2 * (b * 32 + (t >> 2)) + 1];
    float w = gnw[t];
    sc[t] = rstd * w;
    sh[t] = gnb[t] - mean * rstd * w;
  }
  __syncthreads();
  const float4* xb4 = (const float4*)(x + (size_t)b * CH * NSP);
#pragma unroll
  for (int i = 0; i < 8; ++i) {
    int idx = t + i * 256;
    int c = idx >> 4, j4 = idx & 15;
    float4 vv = xb4[(size_t)c * (NSP / 4) + (n0 >> 2) + j4];
    float s_ = sc[c], h_ = sh[c];
    tile[j4 * 4 + 0][c] = vv.x * s_ + h_;
    tile[j4 * 4 + 1][c] = vv.y * s_ + h_;
    tile[j4 * 4 + 2][c] = vv.z * s_ + h_;
    tile[j4 * 4 + 3][c] = vv.w * s_ + h_;
  }
  __syncthreads();

  int wave = t >> 6, lane = t & 63;
  int lr = lane & 15, lg = lane >> 4;
  int n_base = n0 + wave * 16;
  int row = wave * 16 + lr;

  bf16x8 xfr[4];
#pragma unroll
  for (int kk = 0; kk < 4; ++kk) {
    const float* p = &tile[row][kk * 32 + lg * 8];
    f32x4 lo = *(const f32x4*)p;
    f32x4 hi = *(const f32x4*)(p + 4);
    u32x4 xw = {cvt_pk(lo[0], lo[1]), cvt_pk(lo[2], lo[3]),
                cvt_pk(hi[0], hi[1]), cvt_pk(hi[2], hi[3])};
    xfr[kk] = __builtin_bit_cast(bf16x8, xw);
  }

  f32x4 accq[8] = {}, acck[8] = {}, accv[8] = {};
#pragma unroll
  for (int kk = 0; kk < 4; ++kk) {
    int coff = kk * 32 + lg * 8;
    bf16x8 xa = xfr[kk];
#pragma unroll
    for (int ot = 0; ot < 8; ++ot) {
      int woff = (ot * 16 + lr) * CH + coff;
      bf16x8 wqf = ld_bf8(wqb + woff);
      bf16x8 wkf = ld_bf8(wkb + woff);
      bf16x8 wvf = ld_bf8(wvb + woff);
      accq[ot] = mfma16(xa, wqf, accq[ot]);
      acck[ot] = mfma16(xa, wkf, acck[ot]);
      accv[ot] = mfma16(wvf, xa, accv[ot]);
    }
  }
  const float qscale = 0.08838834764831845f * LOG2E;  // log2e/sqrt(128)
  // v-store fragment coords for this lane: key jj = wave*16 + lr within the tile
  int jj = wave * 16 + lr;
  int frv = (jj >> 5) * 4 + ((jj & 15) >> 2);  // kk2*4 + lg_v
  int ev = (lr & 3) + ((wave & 1) << 2);       // element within fragment
#pragma unroll
  for (int ot = 0; ot < 8; ++ot) {
    int o_col = ot * 16 + lr;
    float bqv = bq[o_col], bkv = bk[o_col];
#pragma unroll
    for (int r = 0; r < 4; ++r) {
      int nrow = n_base + lg * 4 + r;
      q[((size_t)b * NSP + nrow) * CH + o_col] = f2bf((accq[ot][r] + bqv) * qscale);
      int cperm = ((((o_col >> 3) ^ (nrow & 7)) << 3)) | (o_col & 7);
      k[((size_t)b * NSP + nrow) * CH + cperm] = f2bf(acck[ot][r] + bkv);
    }
#pragma unroll
    for (int r = 0; r < 4; ++r) {
      int c = ot * 16 + lg * 4 + r;  // v output channel
      int slot = frv ^ (c & 7);
      v[((size_t)(b * CH + c)) * NSP + blockIdx.x * 64 + slot * 8 + ev] =
          f2bf(accv[ot][r] + bv[c]);
    }
  }
}

// ---------------- flash attention (no-max, KV-split=2, gl2lds double-buffer) --------
// r14 schedule with the staging mechanism swapped to global_load_lds:
// ONE vmcnt(0) + ONE barrier per iteration; no ds_writes, no lgkmcnt, no staging
// registers. Stages for tile t+1 issue right after barrier(t) into the OPPOSITE
// buffers (WAR-safe: barrier(t) guarantees no wave still reads buffer cur^1) and
// have a full compute phase to land. Pre-permuted global K/V layouts (qkv) give
// linear LDS dests + XOR-slot conflict-free ds_reads (r12/r15-verified).
__global__ __launch_bounds__(256, 2) void attn_kernel(const u16* __restrict__ q,
                                                      const u16* __restrict__ k,
                                                      const u16* __restrict__ v,
                                                      u16* __restrict__ part0,
                                                      u16* __restrict__ part1,
                                                      float* __restrict__ lbuf) {
  __shared__ __align__(16) u16 kbuf[2][64 * 128];  // 2 x 16 KB
  __shared__ __align__(16) u16 vbuf[2][128 * 64];  // 2 x 16 KB
  int id = blockIdx.x;
  int b = id & 7;
  int qblk = (id >> 3) & 31;
  int split = id >> 8;  // 0 or 1
  int wave = threadIdx.x >> 6, lane = threadIdx.x & 63;
  int lr = lane & 15, lg = lane >> 4;
  int i_base = qblk * 128 + wave * 32;
  int t0 = split * 32, t1 = t0 + 32;

  const u16* kg = k + (size_t)b * NSP * CH;
  const u16* vg = v + (size_t)b * CH * NSP;

  // Q fragments (B-operand: q-row at lane&15), 2 q-tiles x 4 k-chunks
  bf16x8 qa[2][4];
#pragma unroll
  for (int qt = 0; qt < 2; ++qt) {
    const u16* qrow = q + ((size_t)b * NSP + i_base + qt * 16 + lr) * CH;
#pragma unroll
    for (int kk = 0; kk < 4; ++kk) qa[qt][kk] = ld_bf8(qrow + kk * 32 + lg * 8);
  }

  // staging (linear): K = 4 x 1024B (4 rows of 256B); V = 4 x 1024B (8 rows of 128B)
  auto STAGEK = [&](int t, int bi) {
    const u16* src = kg + ((size_t)(t * 64 + wave * 16)) * CH + lane * 8;
    u16* dst = &kbuf[bi][wave * 16 * 128];
#pragma unroll
    for (int g = 0; g < 4; ++g) gl2lds16(src + g * 512, dst + g * 512);
  };
  int vco = wave * 32 + (lane >> 3);
  auto STAGEV = [&](int t, int bi) {
    const u16* src = vg + t * 64 + (lane & 7) * 8;
    u16* dst = &vbuf[bi][wave * 32 * 64];
#pragma unroll
    for (int g = 0; g < 4; ++g) gl2lds16(src + (size_t)(vco + g * 8) * NSP, dst + g * 512);
  };

  STAGEK(t0, 0);
  STAGEV(t0, 0);

  f32x4 oacc[2][8] = {};
  float lsum[2] = {0.f, 0.f};

  for (int t = t0; t < t1; ++t) {
    int cur = (t - t0) & 1;
    const u16* kb = kbuf[cur];
    const u16* vb = vbuf[cur];
    asm volatile("s_waitcnt vmcnt(0)" ::: "memory");  // my stages for tile t arrived
    __builtin_amdgcn_s_barrier();                     // all stages visible; cur^1 free
    __builtin_amdgcn_sched_barrier(0);
    if (t + 1 < t1) {  // fire-and-forget into opposite buffers; full iter to land
      STAGEK(t + 1, cur ^ 1);
      STAGEV(t + 1, cur ^ 1);
    }
    __builtin_amdgcn_sched_barrier(0);

    // ---- S^T = K Q^T : lane holds 16 scores for q-row lr (per qt) ----
    f32x4 s[2][4] = {};
    __builtin_amdgcn_s_setprio(1);
#pragma unroll
    for (int kk = 0; kk < 4; ++kk) {
#pragma unroll
      for (int jt = 0; jt < 4; ++jt) {
        int row = jt * 16 + lr;
        bf16x8 kf = ld_bf8(kb + row * 128 + ((((kk << 2) + lg) ^ (row & 7)) << 3));
        s[0][jt] = mfma16(kf, qa[0][kk], s[0][jt]);
        s[1][jt] = mfma16(kf, qa[1][kk], s[1][jt]);
      }
    }
    __builtin_amdgcn_s_setprio(0);

    // ---- softmax+PV interleaved per key-half kk2 ----
#pragma unroll
    for (int kk2 = 0; kk2 < 2; ++kk2) {
      u32x4 paw[2];
#pragma unroll
      for (int qt = 0; qt < 2; ++qt) {
        float p0 = fast_exp2(s[qt][2 * kk2][0]);
        float p1 = fast_exp2(s[qt][2 * kk2][1]);
        float p2 = fast_exp2(s[qt][2 * kk2][2]);
        float p3 = fast_exp2(s[qt][2 * kk2][3]);
        float p4 = fast_exp2(s[qt][2 * kk2 + 1][0]);
        float p5 = fast_exp2(s[qt][2 * kk2 + 1][1]);
        float p6 = fast_exp2(s[qt][2 * kk2 + 1][2]);
        float p7 = fast_exp2(s[qt][2 * kk2 + 1][3]);
        lsum[qt] += ((p0 + p1) + (p2 + p3)) + ((p4 + p5) + (p6 + p7));
        paw[qt][0] = cvt_pk(p0, p1);
        paw[qt][1] = cvt_pk(p2, p3);
        paw[qt][2] = cvt_pk(p4, p5);
        paw[qt][3] = cvt_pk(p6, p7);
      }
      bf16x8 pa0 = __builtin_bit_cast(bf16x8, paw[0]);
      bf16x8 pa1 = __builtin_bit_cast(bf16x8, paw[1]);
      __builtin_amdgcn_s_setprio(1);
#pragma unroll
      for (int ct = 0; ct < 8; ++ct) {
        int c = ct * 16 + lr;
        bf16x8 vf = ld_bf8(vb + c * 64 + ((((kk2 << 2) + lg) ^ (c & 7)) << 3));
        oacc[0][ct] = mfma16(pa0, vf, oacc[0][ct]);
        oacc[1][ct] = mfma16(pa1, vf, oacc[1][ct]);
      }
      __builtin_amdgcn_s_setprio(0);
    }
  }

  // ---- epilogue: reduce l across lane groups; write unnormalized partial ----
  u16* pdst = (split == 0) ? part0 : part1;
  float* ldst = lbuf + (size_t)split * (BATCH * NSP) + (size_t)b * NSP;
#pragma unroll
  for (int qt = 0; qt < 2; ++qt) {
    lsum[qt] += __shfl_xor(lsum[qt], 16);
    lsum[qt] += __shfl_xor(lsum[qt], 32);
    if (lg == 0) ldst[i_base + qt * 16 + lr] = lsum[qt];
#pragma unroll
    for (int r = 0; r < 4; ++r) {
      int i = i_base + qt * 16 + lg * 4 + r;
      u16* row = pdst + ((size_t)b * NSP + i) * CH;
#pragma unroll
      for (int ct = 0; ct < 8; ++ct) row[ct * 16 + lr] = f2bf(oacc[qt][ct][r]);
    }
  }
}

// ---------------- output projection + residual (combines the 2 KV-split partials) ----
__global__ __launch_bounds__(256) void proj_kernel(const u16* __restrict__ p0,
                                                   const u16* __restrict__ p1,
                                                   const float* __restrict__ lbuf,
                                                   const u16* __restrict__ wob,
                                                   const float* __restrict__ bo,
                                                   const float* __restrict__ gamma,
                                                   const float* __restrict__ x,
                                                   float* __restrict__ out) {
  int b = blockIdx.y;
  int wave = threadIdx.x >> 6, lane = threadIdx.x & 63;
  int lr = lane & 15, lg = lane >> 4;
  int n_base = blockIdx.x * 64 + wave * 16;
  int nrow = n_base + lr;
  float linv = 1.f / (lbuf[(size_t)b * NSP + nrow] +
                      lbuf[(size_t)BATCH * NSP + (size_t)b * NSP + nrow]);
  const u16* r0 = p0 + ((size_t)b * NSP + nrow) * CH;
  const u16* r1 = p1 + ((size_t)b * NSP + nrow) * CH;
  f32x4 acc[8] = {};
#pragma unroll
  for (int kk = 0; kk < 4; ++kk) {
    int coff = kk * 32 + lg * 8;
    bf16x8 a = ld_bf8(r0 + coff);
    bf16x8 bb = ld_bf8(r1 + coff);
    u32 w0 = cvt_pk(((float)a[0] + (float)bb[0]) * linv, ((float)a[1] + (float)bb[1]) * linv);
    u32 w1 = cvt_pk(((float)a[2] + (float)bb[2]) * linv, ((float)a[3] + (float)bb[3]) * linv);
    u32 w2 = cvt_pk(((float)a[4] + (float)bb[4]) * linv, ((float)a[5] + (float)bb[5]) * linv);
    u32 w3 = cvt_pk(((float)a[6] + (float)bb[6]) * linv, ((float)a[7] + (float)bb[7]) * linv);
    u32x4 wv = {w0, w1, w2, w3};
    bf16x8 ofrag = __builtin_bit_cast(bf16x8, wv);
#pragma unroll
    for (int ot = 0; ot < 8; ++ot) {
      bf16x8 wf = ld_bf8(wob + (ot * 16 + lr) * CH + coff);
      acc[ot] = mfma16(wf, ofrag, acc[ot]);
    }
  }
  float g = gamma[0];
  int n_col = n_base + lr;
#pragma unroll
  for (int ot = 0; ot < 8; ++ot) {
#pragma unroll
    for (int r = 0; r < 4; ++r) {
      int o_row = ot * 16 + lg * 4 + r;
      size_t off = ((size_t)b * CH + o_row) * NSP + n_col;
      out[off] = x[off] + g * (acc[ot][r] + bo[o_row]);
    }
  }
}

extern "C" void kernel_launch(void* const* d_in, const int* in_sizes, int n_in,
                              void* d_out, int out_size, void* d_ws, size_t ws_size,
                              hipStream_t stream) {
  const float* x = (const float*)d_in[0];
  const float* gnw = (const float*)d_in[1];
  const float* gnb = (const float*)d_in[2];
  const float* wq = (const float*)d_in[3];
  const float* bq = (const float*)d_in[4];
  const float* wk = (const float*)d_in[5];
  const float* bk = (const float*)d_in[6];
  const float* wv = (const float*)d_in[7];
  const float* bv = (const float*)d_in[8];
  const float* wo = (const float*)d_in[9];
  const float* bo = (const float*)d_in[10];
  const float* gamma = (const float*)d_in[11];
  float* out = (float*)d_out;

  const size_t BUF = (size_t)BATCH * NSP * CH * sizeof(u16);  // 8 MB
  char* ws = (char*)d_ws;
  u16* wbf = (u16*)ws;             // 4 x 128x128 bf16 = 128KB
  float* stats = (float*)(ws + 131072);
  u16* xd = (u16*)(ws + 262144);   // split0 partial O
  u16* qb = (u16*)(ws + 262144 + BUF);
  u16* kb = (u16*)(ws + 262144 + 2 * BUF);
  u16* vb = (u16*)(ws + 262144 + 3 * BUF);
  float* lbuf = (float*)(ws + 262144 + 4 * BUF);  // 2 x 32768 f32 = 256KB
  const size_t need = 262144 + 4 * BUF + 262144;
  if (ws_size < need) return;
  // split1 partial: prefer extra ws space; else reuse qb (Q read only in attn prologue;
  // grid=512 at 2 blocks/CU is fully co-resident, epilogue writes land long after reads)
  u16* part1 = (ws_size >= need + BUF) ? (u16*)(ws + need) : qb;

  gn_stats_kernel<<<256, 256, 0, stream>>>(x, stats, wq, wk, wv, wo, wbf);
  qkv_kernel<<<dim3(64, 8), 256, 0, stream>>>(x, stats, gnw, gnb, wbf, wbf + 16384,
                                              wbf + 32768, bq, bk, bv, qb, kb, vb);
  attn_kernel<<<512, 256, 0, stream>>>(qb, kb, vb, xd, part1, lbuf);
  proj_kernel<<<dim3(64, 8), 256, 0, stream>>>(xd, part1, lbuf, wbf + 49152, bo, gamma,
                                               x, out);
}

// Round 18
// 127.355 us; speedup vs baseline: 1.1129x; 1.0000x over previous
//
#include <hip/hip_runtime.h>

typedef unsigned short u16;
typedef unsigned int u32;
typedef __bf16 bf16_t;
typedef bf16_t bf16x8 __attribute__((ext_vector_type(8)));
typedef float f32x4 __attribute__((ext_vector_type(4)));
typedef u32 u32x4 __attribute__((ext_vector_type(4)));

#define BATCH 8
#define CH 128
#define NSP 4096  // 64*64 spatial
#define LOG2E 1.44269504088896f

static __device__ __forceinline__ u16 f2bf(float f) {
  u32 u = __builtin_bit_cast(u32, f);
  u32 r = u + 0x7FFFu + ((u >> 16) & 1u);  // RNE
  return (u16)(r >> 16);
}

static __device__ __forceinline__ bf16x8 ld_bf8(const u16* p) {
  return __builtin_bit_cast(bf16x8, *(const u32x4*)p);
}

static __device__ __forceinline__ f32x4 mfma16(bf16x8 a, bf16x8 b, f32x4 c) {
  return __builtin_amdgcn_mfma_f32_16x16x32_bf16(a, b, c, 0, 0, 0);
}

static __device__ __forceinline__ u32 cvt_pk(float lo, float hi) {
  u32 r;
  asm("v_cvt_pk_bf16_f32 %0, %1, %2" : "=v"(r) : "v"(lo), "v"(hi));
  return r;
}

static __device__ __forceinline__ float fast_exp2(float x) {
#if __has_builtin(__builtin_amdgcn_exp2f)
  return __builtin_amdgcn_exp2f(x);
#else
  return exp2f(x);
#endif
}

static __device__ __forceinline__ void gl2lds16(const u16* g, u16* l) {
  __builtin_amdgcn_global_load_lds((const __attribute__((address_space(1))) void*)g,
                                   (__attribute__((address_space(3))) void*)l, 16, 0, 0);
}

// ---------------- GroupNorm stats (+ fused weight fp32->bf16 convert) ----------------
__global__ __launch_bounds__(256) void gn_stats_kernel(const float* __restrict__ x,
                                                       float* __restrict__ stats,
                                                       const float* __restrict__ wq,
                                                       const float* __restrict__ wk,
                                                       const float* __restrict__ wv,
                                                       const float* __restrict__ wo,
                                                       u16* __restrict__ wbf) {
  int bg = blockIdx.x;  // 0..255
  {
    int widx = bg * 256 + threadIdx.x;
    int m = widx >> 14, r = widx & 16383;
    const float* s = (m == 0) ? wq : (m == 1) ? wk : (m == 2) ? wv : wo;
    wbf[widx] = f2bf(s[r]);
  }
  const float4* p = (const float4*)(x + (size_t)bg * 16384);
  float s = 0.f, ss = 0.f;
  for (int i = threadIdx.x; i < 4096; i += 256) {
    float4 v = p[i];
    s += v.x + v.y + v.z + v.w;
    ss += v.x * v.x + v.y * v.y + v.z * v.z + v.w * v.w;
  }
  for (int off = 32; off; off >>= 1) {
    s += __shfl_xor(s, off);
    ss += __shfl_xor(ss, off);
  }
  __shared__ float rs[4], rss[4];
  int wave = threadIdx.x >> 6;
  if ((threadIdx.x & 63) == 0) { rs[wave] = s; rss[wave] = ss; }
  __syncthreads();
  if (threadIdx.x == 0) {
    s = rs[0] + rs[1] + rs[2] + rs[3];
    ss = rss[0] + rss[1] + rss[2] + rss[3];
    float mean = s * (1.f / 16384.f);
    float var = ss * (1.f / 16384.f) - mean * mean;
    stats[2 * bg] = mean;
    stats[2 * bg + 1] = rsqrtf(var + 1e-5f);
  }
}

// ---------------- fused GN-apply + QKV projections (permuted K/V outputs) ----------------
// Reads x (b,c,n) directly, applies GN, transposes via f32 LDS tile, then 3 GEMMs.
// q: (b,n,c) bf16, pre-scaled by log2e/sqrt(C).
// k: (b,n,c') bf16, c' = ((c>>3) ^ (n&7))*8 + (c&7): linear gl2lds staging then
//    reading fragment (kk,lg) at slot (kk*4+lg)^(n&7) is correct + conflict-free.
// v: (b,c,j') bf16 in PV-fragment order: fragment fr = kk2*4+lg at slot fr^(c&7);
//    element e of key jj: kk2 = jj>>5, lg = (jj&15)>>2, e = (jj&3)+(jj&16?4:0).
__global__ __launch_bounds__(256) void qkv_kernel(const float* __restrict__ x,
                                                  const float* __restrict__ stats,
                                                  const float* __restrict__ gnw,
                                                  const float* __restrict__ gnb,
                                                  const u16* __restrict__ wqb,
                                                  const u16* __restrict__ wkb,
                                                  const u16* __restrict__ wvb,
                                                  const float* __restrict__ bq,
                                                  const float* __restrict__ bk,
                                                  const float* __restrict__ bv,
                                                  u16* __restrict__ q, u16* __restrict__ k,
                                                  u16* __restrict__ v) {
  __shared__ float tile[64][132];  // x^T tile (n-local, c) f32; stride 132 keeps b128 reads clean
  __shared__ float sc[128], sh[128];
  int b = blockIdx.y;
  int n0 = blockIdx.x * 64;
  int t = threadIdx.x;
  if (t < 128) {
    float mean = stats[2 * (b * 32 + (t >> 2))];
    float rstd = stats[2 * (b * 32 + (t >> 2)) + 1];
    float w = gnw[t];
    sc[t] = rstd * w;
    sh[t] = gnb[t] - mean * rstd * w;
  }
  __syncthreads();
  const float4* xb4 = (const float4*)(x + (size_t)b * CH * NSP);
#pragma unroll
  for (int i = 0; i < 8; ++i) {
    int idx = t + i * 256;
    int c = idx >> 4, j4 = idx & 15;
    float4 vv = xb4[(size_t)c * (NSP / 4) + (n0 >> 2) + j4];
    float s_ = sc[c], h_ = sh[c];
    tile[j4 * 4 + 0][c] = vv.x * s_ + h_;
    tile[j4 * 4 + 1][c] = vv.y * s_ + h_;
    tile[j4 * 4 + 2][c] = vv.z * s_ + h_;
    tile[j4 * 4 + 3][c] = vv.w * s_ + h_;
  }
  __syncthreads();

  int wave = t >> 6, lane = t & 63;
  int lr = lane & 15, lg = lane >> 4;
  int n_base = n0 + wave * 16;
  int row = wave * 16 + lr;

  bf16x8 xfr[4];
#pragma unroll
  for (int kk = 0; kk < 4; ++kk) {
    const float* p = &tile[row][kk * 32 + lg * 8];
    f32x4 lo = *(const f32x4*)p;
    f32x4 hi = *(const f32x4*)(p + 4);
    u32x4 xw = {cvt_pk(lo[0], lo[1]), cvt_pk(lo[2], lo[3]),
                cvt_pk(hi[0], hi[1]), cvt_pk(hi[2], hi[3])};
    xfr[kk] = __builtin_bit_cast(bf16x8, xw);
  }

  f32x4 accq[8] = {}, acck[8] = {}, accv[8] = {};
#pragma unroll
  for (int kk = 0; kk < 4; ++kk) {
    int coff = kk * 32 + lg * 8;
    bf16x8 xa = xfr[kk];
#pragma unroll
    for (int ot = 0; ot < 8; ++ot) {
      int woff = (ot * 16 + lr) * CH + coff;
      bf16x8 wqf = ld_bf8(wqb + woff);
      bf16x8 wkf = ld_bf8(wkb + woff);
      bf16x8 wvf = ld_bf8(wvb + woff);
      accq[ot] = mfma16(xa, wqf, accq[ot]);
      acck[ot] = mfma16(xa, wkf, acck[ot]);
      accv[ot] = mfma16(wvf, xa, accv[ot]);
    }
  }
  const float qscale = 0.08838834764831845f * LOG2E;  // log2e/sqrt(128)
  // v-store fragment coords for this lane: key jj = wave*16 + lr within the tile
  int jj = wave * 16 + lr;
  int frv = (jj >> 5) * 4 + ((jj & 15) >> 2);  // kk2*4 + lg_v
  int ev = (lr & 3) + ((wave & 1) << 2);       // element within fragment
#pragma unroll
  for (int ot = 0; ot < 8; ++ot) {
    int o_col = ot * 16 + lr;
    float bqv = bq[o_col], bkv = bk[o_col];
#pragma unroll
    for (int r = 0; r < 4; ++r) {
      int nrow = n_base + lg * 4 + r;
      q[((size_t)b * NSP + nrow) * CH + o_col] = f2bf((accq[ot][r] + bqv) * qscale);
      int cperm = ((((o_col >> 3) ^ (nrow & 7)) << 3)) | (o_col & 7);
      k[((size_t)b * NSP + nrow) * CH + cperm] = f2bf(acck[ot][r] + bkv);
    }
#pragma unroll
    for (int r = 0; r < 4; ++r) {
      int c = ot * 16 + lg * 4 + r;  // v output channel
      int slot = frv ^ (c & 7);
      v[((size_t)(b * CH + c)) * NSP + blockIdx.x * 64 + slot * 8 + ev] =
          f2bf(accv[ot][r] + bv[c]);
    }
  }
}

// ---------------- flash attention (no-max, KV-split=2, gl2lds double-buffer) --------
// r17 structure (80.4us verified best) with three chain-surgery tweaks:
// 1) l-sum via MFMA against all-ones B fragment (removes 28 serial v_adds from
//    the exp2->cvt_pk critical path; epilogue shuffles gone; l consistent with
//    the bf16 P used by PV).
// 2) staging split: K(t+1) issues right after the barrier, V(t+1) after the QK
//    cluster (V not needed until next iter's PV; stops V-stage competing with
//    the first kf ds_read burst).
// 3) one sched_barrier only (scheduler may mix first kf reads with stage issue).
__global__ __launch_bounds__(256, 2) void attn_kernel(const u16* __restrict__ q,
                                                      const u16* __restrict__ k,
                                                      const u16* __restrict__ v,
                                                      u16* __restrict__ part0,
                                                      u16* __restrict__ part1,
                                                      float* __restrict__ lbuf) {
  __shared__ __align__(16) u16 kbuf[2][64 * 128];  // 2 x 16 KB
  __shared__ __align__(16) u16 vbuf[2][128 * 64];  // 2 x 16 KB
  int id = blockIdx.x;
  int b = id & 7;
  int qblk = (id >> 3) & 31;
  int split = id >> 8;  // 0 or 1
  int wave = threadIdx.x >> 6, lane = threadIdx.x & 63;
  int lr = lane & 15, lg = lane >> 4;
  int i_base = qblk * 128 + wave * 32;
  int t0 = split * 32, t1 = t0 + 32;

  const u16* kg = k + (size_t)b * NSP * CH;
  const u16* vg = v + (size_t)b * CH * NSP;

  // Q fragments (B-operand: q-row at lane&15), 2 q-tiles x 4 k-chunks
  bf16x8 qa[2][4];
#pragma unroll
  for (int qt = 0; qt < 2; ++qt) {
    const u16* qrow = q + ((size_t)b * NSP + i_base + qt * 16 + lr) * CH;
#pragma unroll
    for (int kk = 0; kk < 4; ++kk) qa[qt][kk] = ld_bf8(qrow + kk * 32 + lg * 8);
  }

  // staging (linear): K = 4 x 1024B (4 rows of 256B); V = 4 x 1024B (8 rows of 128B)
  auto STAGEK = [&](int t, int bi) {
    const u16* src = kg + ((size_t)(t * 64 + wave * 16)) * CH + lane * 8;
    u16* dst = &kbuf[bi][wave * 16 * 128];
#pragma unroll
    for (int g = 0; g < 4; ++g) gl2lds16(src + g * 512, dst + g * 512);
  };
  int vco = wave * 32 + (lane >> 3);
  auto STAGEV = [&](int t, int bi) {
    const u16* src = vg + t * 64 + (lane & 7) * 8;
    u16* dst = &vbuf[bi][wave * 32 * 64];
#pragma unroll
    for (int g = 0; g < 4; ++g) gl2lds16(src + (size_t)(vco + g * 8) * NSP, dst + g * 512);
  };

  STAGEK(t0, 0);
  STAGEV(t0, 0);

  // all-ones B fragment for l row-sums via MFMA
  const u32x4 ones_u = {0x3F803F80u, 0x3F803F80u, 0x3F803F80u, 0x3F803F80u};
  const bf16x8 ones = __builtin_bit_cast(bf16x8, ones_u);

  f32x4 oacc[2][8] = {};
  f32x4 lacc[2] = {};

  for (int t = t0; t < t1; ++t) {
    int cur = (t - t0) & 1;
    const u16* kb = kbuf[cur];
    const u16* vb = vbuf[cur];
    asm volatile("s_waitcnt vmcnt(0)" ::: "memory");  // my stages for tile t arrived
    __builtin_amdgcn_s_barrier();                     // all stages visible; cur^1 free
    __builtin_amdgcn_sched_barrier(0);
    if (t + 1 < t1) STAGEK(t + 1, cur ^ 1);  // K first: needed at top of next iter

    // ---- S^T = K Q^T : lane holds 16 scores for q-row lr (per qt) ----
    f32x4 s[2][4] = {};
    __builtin_amdgcn_s_setprio(1);
#pragma unroll
    for (int kk = 0; kk < 4; ++kk) {
#pragma unroll
      for (int jt = 0; jt < 4; ++jt) {
        int row = jt * 16 + lr;
        bf16x8 kf = ld_bf8(kb + row * 128 + ((((kk << 2) + lg) ^ (row & 7)) << 3));
        s[0][jt] = mfma16(kf, qa[0][kk], s[0][jt]);
        s[1][jt] = mfma16(kf, qa[1][kk], s[1][jt]);
      }
    }
    __builtin_amdgcn_s_setprio(0);
    if (t + 1 < t1) STAGEV(t + 1, cur ^ 1);  // V needed only at next iter's PV

    // ---- softmax+PV interleaved per key-half kk2; l-sums via MFMA(P, ones) ----
#pragma unroll
    for (int kk2 = 0; kk2 < 2; ++kk2) {
      u32x4 paw[2];
#pragma unroll
      for (int qt = 0; qt < 2; ++qt) {
        float p0 = fast_exp2(s[qt][2 * kk2][0]);
        float p1 = fast_exp2(s[qt][2 * kk2][1]);
        float p2 = fast_exp2(s[qt][2 * kk2][2]);
        float p3 = fast_exp2(s[qt][2 * kk2][3]);
        float p4 = fast_exp2(s[qt][2 * kk2 + 1][0]);
        float p5 = fast_exp2(s[qt][2 * kk2 + 1][1]);
        float p6 = fast_exp2(s[qt][2 * kk2 + 1][2]);
        float p7 = fast_exp2(s[qt][2 * kk2 + 1][3]);
        paw[qt][0] = cvt_pk(p0, p1);
        paw[qt][1] = cvt_pk(p2, p3);
        paw[qt][2] = cvt_pk(p4, p5);
        paw[qt][3] = cvt_pk(p6, p7);
      }
      bf16x8 pa0 = __builtin_bit_cast(bf16x8, paw[0]);
      bf16x8 pa1 = __builtin_bit_cast(bf16x8, paw[1]);
      __builtin_amdgcn_s_setprio(1);
      lacc[0] = mfma16(pa0, ones, lacc[0]);
      lacc[1] = mfma16(pa1, ones, lacc[1]);
#pragma unroll
      for (int ct = 0; ct < 8; ++ct) {
        int c = ct * 16 + lr;
        bf16x8 vf = ld_bf8(vb + c * 64 + ((((kk2 << 2) + lg) ^ (c & 7)) << 3));
        oacc[0][ct] = mfma16(pa0, vf, oacc[0][ct]);
        oacc[1][ct] = mfma16(pa1, vf, oacc[1][ct]);
      }
      __builtin_amdgcn_s_setprio(0);
    }
  }

  // ---- epilogue: write unnormalized partial (bf16) + l (f32, from lacc) ----
  u16* pdst = (split == 0) ? part0 : part1;
  float* ldst = lbuf + (size_t)split * (BATCH * NSP) + (size_t)b * NSP;
#pragma unroll
  for (int qt = 0; qt < 2; ++qt) {
#pragma unroll
    for (int r = 0; r < 4; ++r) {
      int i = i_base + qt * 16 + lg * 4 + r;
      if (lr == 0) ldst[i] = lacc[qt][r];  // row i replicated across cols; col 0 writes
      u16* row = pdst + ((size_t)b * NSP + i) * CH;
#pragma unroll
      for (int ct = 0; ct < 8; ++ct) row[ct * 16 + lr] = f2bf(oacc[qt][ct][r]);
    }
  }
}

// ---------------- output projection + residual (combines the 2 KV-split partials) ----
__global__ __launch_bounds__(256) void proj_kernel(const u16* __restrict__ p0,
                                                   const u16* __restrict__ p1,
                                                   const float* __restrict__ lbuf,
                                                   const u16* __restrict__ wob,
                                                   const float* __restrict__ bo,
                                                   const float* __restrict__ gamma,
                                                   const float* __restrict__ x,
                                                   float* __restrict__ out) {
  int b = blockIdx.y;
  int wave = threadIdx.x >> 6, lane = threadIdx.x & 63;
  int lr = lane & 15, lg = lane >> 4;
  int n_base = blockIdx.x * 64 + wave * 16;
  int nrow = n_base + lr;
  float linv = 1.f / (lbuf[(size_t)b * NSP + nrow] +
                      lbuf[(size_t)BATCH * NSP + (size_t)b * NSP + nrow]);
  const u16* r0 = p0 + ((size_t)b * NSP + nrow) * CH;
  const u16* r1 = p1 + ((size_t)b * NSP + nrow) * CH;
  f32x4 acc[8] = {};
#pragma unroll
  for (int kk = 0; kk < 4; ++kk) {
    int coff = kk * 32 + lg * 8;
    bf16x8 a = ld_bf8(r0 + coff);
    bf16x8 bb = ld_bf8(r1 + coff);
    u32 w0 = cvt_pk(((float)a[0] + (float)bb[0]) * linv, ((float)a[1] + (float)bb[1]) * linv);
    u32 w1 = cvt_pk(((float)a[2] + (float)bb[2]) * linv, ((float)a[3] + (float)bb[3]) * linv);
    u32 w2 = cvt_pk(((float)a[4] + (float)bb[4]) * linv, ((float)a[5] + (float)bb[5]) * linv);
    u32 w3 = cvt_pk(((float)a[6] + (float)bb[6]) * linv, ((float)a[7] + (float)bb[7]) * linv);
    u32x4 wv = {w0, w1, w2, w3};
    bf16x8 ofrag = __builtin_bit_cast(bf16x8, wv);
#pragma unroll
    for (int ot = 0; ot < 8; ++ot) {
      bf16x8 wf = ld_bf8(wob + (ot * 16 + lr) * CH + coff);
      acc[ot] = mfma16(wf, ofrag, acc[ot]);
    }
  }
  float g = gamma[0];
  int n_col = n_base + lr;
#pragma unroll
  for (int ot = 0; ot < 8; ++ot) {
#pragma unroll
    for (int r = 0; r < 4; ++r) {
      int o_row = ot * 16 + lg * 4 + r;
      size_t off = ((size_t)b * CH + o_row) * NSP + n_col;
      out[off] = x[off] + g * (acc[ot][r] + bo[o_row]);
    }
  }
}

extern "C" void kernel_launch(void* const* d_in, const int* in_sizes, int n_in,
                              void* d_out, int out_size, void* d_ws, size_t ws_size,
                              hipStream_t stream) {
  const float* x = (const float*)d_in[0];
  const float* gnw = (const float*)d_in[1];
  const float* gnb = (const float*)d_in[2];
  const float* wq = (const float*)d_in[3];
  const float* bq = (const float*)d_in[4];
  const float* wk = (const float*)d_in[5];
  const float* bk = (const float*)d_in[6];
  const float* wv = (const float*)d_in[7];
  const float* bv = (const float*)d_in[8];
  const float* wo = (const float*)d_in[9];
  const float* bo = (const float*)d_in[10];
  const float* gamma = (const float*)d_in[11];
  float* out = (float*)d_out;

  const size_t BUF = (size_t)BATCH * NSP * CH * sizeof(u16);  // 8 MB
  char* ws = (char*)d_ws;
  u16* wbf = (u16*)ws;             // 4 x 128x128 bf16 = 128KB
  float* stats = (float*)(ws + 131072);
  u16* xd = (u16*)(ws + 262144);   // split0 partial O
  u16* qb = (u16*)(ws + 262144 + BUF);
  u16* kb = (u16*)(ws + 262144 + 2 * BUF);
  u16* vb = (u16*)(ws + 262144 + 3 * BUF);
  float* lbuf = (float*)(ws + 262144 + 4 * BUF);  // 2 x 32768 f32 = 256KB
  const size_t need = 262144 + 4 * BUF + 262144;
  if (ws_size < need) return;
  // split1 partial: prefer extra ws space; else reuse qb (Q read only in attn prologue;
  // grid=512 at 2 blocks/CU is fully co-resident, epilogue writes land long after reads)
  u16* part1 = (ws_size >= need + BUF) ? (u16*)(ws + need) : qb;

  gn_stats_kernel<<<256, 256, 0, stream>>>(x, stats, wq, wk, wv, wo, wbf);
  qkv_kernel<<<dim3(64, 8), 256, 0, stream>>>(x, stats, gnw, gnb, wbf, wbf + 16384,
                                              wbf + 32768, bq, bk, bv, qb, kb, vb);
  attn_kernel<<<512, 256, 0, stream>>>(qb, kb, vb, xd, part1, lbuf);
  proj_kernel<<<dim3(64, 8), 256, 0, stream>>>(xd, part1, lbuf, wbf + 49152, bo, gamma,
                                               x, out);
}

// Round 19
// 111.297 us; speedup vs baseline: 1.2734x; 1.1443x over previous
//
#include <hip/hip_runtime.h>

typedef unsigned short u16;
typedef unsigned int u32;
typedef __bf16 bf16_t;
typedef bf16_t bf16x8 __attribute__((ext_vector_type(8)));
typedef float f32x4 __attribute__((ext_vector_type(4)));
typedef u32 u32x4 __attribute__((ext_vector_type(4)));

#define BATCH 8
#define CH 128
#define NSP 4096  // 64*64 spatial
#define LOG2E 1.44269504088896f

static __device__ __forceinline__ u16 f2bf(float f) {
  u32 u = __builtin_bit_cast(u32, f);
  u32 r = u + 0x7FFFu + ((u >> 16) & 1u);  // RNE
  return (u16)(r >> 16);
}

static __device__ __forceinline__ bf16x8 ld_bf8(const u16* p) {
  return __builtin_bit_cast(bf16x8, *(const u32x4*)p);
}

static __device__ __forceinline__ f32x4 mfma16(bf16x8 a, bf16x8 b, f32x4 c) {
  return __builtin_amdgcn_mfma_f32_16x16x32_bf16(a, b, c, 0, 0, 0);
}

static __device__ __forceinline__ u32 cvt_pk(float lo, float hi) {
  u32 r;
  asm("v_cvt_pk_bf16_f32 %0, %1, %2" : "=v"(r) : "v"(lo), "v"(hi));
  return r;
}

static __device__ __forceinline__ float fast_exp2(float x) {
#if __has_builtin(__builtin_amdgcn_exp2f)
  return __builtin_amdgcn_exp2f(x);
#else
  return exp2f(x);
#endif
}

static __device__ __forceinline__ void gl2lds16(const u16* g, u16* l) {
  __builtin_amdgcn_global_load_lds((const __attribute__((address_space(1))) void*)g,
                                   (__attribute__((address_space(3))) void*)l, 16, 0, 0);
}

// ---------------- GroupNorm stats (+ fused weight fp32->bf16 convert) ----------------
__global__ __launch_bounds__(256) void gn_stats_kernel(const float* __restrict__ x,
                                                       float* __restrict__ stats,
                                                       const float* __restrict__ wq,
                                                       const float* __restrict__ wk,
                                                       const float* __restrict__ wv,
                                                       const float* __restrict__ wo,
                                                       u16* __restrict__ wbf) {
  int bg = blockIdx.x;  // 0..255
  {
    int widx = bg * 256 + threadIdx.x;
    int m = widx >> 14, r = widx & 16383;
    const float* s = (m == 0) ? wq : (m == 1) ? wk : (m == 2) ? wv : wo;
    wbf[widx] = f2bf(s[r]);
  }
  const float4* p = (const float4*)(x + (size_t)bg * 16384);
  float s = 0.f, ss = 0.f;
  for (int i = threadIdx.x; i < 4096; i += 256) {
    float4 v = p[i];
    s += v.x + v.y + v.z + v.w;
    ss += v.x * v.x + v.y * v.y + v.z * v.z + v.w * v.w;
  }
  for (int off = 32; off; off >>= 1) {
    s += __shfl_xor(s, off);
    ss += __shfl_xor(ss, off);
  }
  __shared__ float rs[4], rss[4];
  int wave = threadIdx.x >> 6;
  if ((threadIdx.x & 63) == 0) { rs[wave] = s; rss[wave] = ss; }
  __syncthreads();
  if (threadIdx.x == 0) {
    s = rs[0] + rs[1] + rs[2] + rs[3];
    ss = rss[0] + rss[1] + rss[2] + rss[3];
    float mean = s * (1.f / 16384.f);
    float var = ss * (1.f / 16384.f) - mean * mean;
    stats[2 * bg] = mean;
    stats[2 * bg + 1] = rsqrtf(var + 1e-5f);
  }
}

// ---------------- fused GN-apply + QKV projections (weights staged in LDS) ----------
// Reads x (b,c,n), applies GN, transposes via f32 LDS tile, then 3 GEMMs computed
// SEQUENTIALLY, each with its 128x128 bf16 weight matrix staged ONCE into LDS
// (smem unioned with the x-tile: disjoint phases). Staging = linear gl2lds dest +
// inverse-XOR source; fragment reads use slot (kk*4+lg)^(row&7) — the same
// conflict-free pattern as attn's K path. Cuts per-block L2 weight reads 4x
// (and cross-block re-reads come from LDS instead of L2).
// Outputs (verified r12/r15/r17): q (b,n,c) pre-scaled by log2e/sqrt(C);
// k (b,n,c') with c' = ((c>>3)^(n&7))*8 + (c&7); v (b,c,j') in PV-fragment order.
__global__ __launch_bounds__(256) void qkv_kernel(const float* __restrict__ x,
                                                  const float* __restrict__ stats,
                                                  const float* __restrict__ gnw,
                                                  const float* __restrict__ gnb,
                                                  const u16* __restrict__ wqb,
                                                  const u16* __restrict__ wkb,
                                                  const u16* __restrict__ wvb,
                                                  const float* __restrict__ bq,
                                                  const float* __restrict__ bk,
                                                  const float* __restrict__ bv,
                                                  u16* __restrict__ q, u16* __restrict__ k,
                                                  u16* __restrict__ v) {
  __shared__ __align__(16) char smem[64 * 132 * 4];  // union: f32 x-tile | bf16 weights
  __shared__ float sc[128], sh[128];
  float(*tile)[132] = (float(*)[132])smem;
  u16* wbuf = (u16*)smem;  // 128 rows x 128 u16 (32KB), slot-XOR layout
  int b = blockIdx.y;
  int n0 = blockIdx.x * 64;
  int t = threadIdx.x;
  if (t < 128) {
    float mean = stats[2 * (b * 32 + (t >> 2))];
    float rstd = stats[2 * (b * 32 + (t >> 2)) + 1];
    float w = gnw[t];
    sc[t] = rstd * w;
    sh[t] = gnb[t] - mean * rstd * w;
  }
  __syncthreads();
  const float4* xb4 = (const float4*)(x + (size_t)b * CH * NSP);
#pragma unroll
  for (int i = 0; i < 8; ++i) {
    int idx = t + i * 256;
    int c = idx >> 4, j4 = idx & 15;
    float4 vv = xb4[(size_t)c * (NSP / 4) + (n0 >> 2) + j4];
    float s_ = sc[c], h_ = sh[c];
    tile[j4 * 4 + 0][c] = vv.x * s_ + h_;
    tile[j4 * 4 + 1][c] = vv.y * s_ + h_;
    tile[j4 * 4 + 2][c] = vv.z * s_ + h_;
    tile[j4 * 4 + 3][c] = vv.w * s_ + h_;
  }
  __syncthreads();

  int wave = t >> 6, lane = t & 63;
  int lr = lane & 15, lg = lane >> 4;
  int n_base = n0 + wave * 16;
  int row = wave * 16 + lr;

  bf16x8 xfr[4];
#pragma unroll
  for (int kk = 0; kk < 4; ++kk) {
    const float* p = &tile[row][kk * 32 + lg * 8];
    f32x4 lo = *(const f32x4*)p;
    f32x4 hi = *(const f32x4*)(p + 4);
    u32x4 xw = {cvt_pk(lo[0], lo[1]), cvt_pk(lo[2], lo[3]),
                cvt_pk(hi[0], hi[1]), cvt_pk(hi[2], hi[3])};
    xfr[kk] = __builtin_bit_cast(bf16x8, xw);
  }
  __syncthreads();  // all waves done with the x-tile; smem becomes the weight buffer

  // stage one 128x128 bf16 weight matrix: linear LDS dest, inverse-XOR source.
  // instr g writes rows wave*32+g*4 .. +3; lane l -> row +(l>>4), slot l&15;
  // src chunk = (l&15) ^ (row&7)  =>  wbuf[row][s] = w[row][s ^ (row&7)].
  auto STAGEW = [&](const u16* w) {
#pragma unroll
    for (int g = 0; g < 8; ++g) {
      int wr = wave * 32 + g * 4 + (lane >> 4);
      gl2lds16(w + wr * CH + (((lane & 15) ^ (wr & 7)) << 3),
               wbuf + (wave * 32 + g * 4) * 128);
    }
  };
  // fragment read: row = ot*16+lr, slot (kk*4+lg)^(row&7) -> w[row][chunk kk*4+lg]
  auto WFRAG = [&](int ot, int kk) {
    int wr = ot * 16 + lr;
    return ld_bf8(wbuf + wr * 128 + ((((kk << 2) + lg) ^ (wr & 7)) << 3));
  };

  const float qscale = 0.08838834764831845f * LOG2E;  // log2e/sqrt(128)

  // ---------------- Q ----------------
  STAGEW(wqb);
  asm volatile("s_waitcnt vmcnt(0)" ::: "memory");
  __syncthreads();
  {
    f32x4 acc[8] = {};
#pragma unroll
    for (int kk = 0; kk < 4; ++kk)
#pragma unroll
      for (int ot = 0; ot < 8; ++ot) acc[ot] = mfma16(xfr[kk], WFRAG(ot, kk), acc[ot]);
#pragma unroll
    for (int ot = 0; ot < 8; ++ot) {
      int o_col = ot * 16 + lr;
      float bqv = bq[o_col];
#pragma unroll
      for (int r = 0; r < 4; ++r) {
        int nrow = n_base + lg * 4 + r;
        q[((size_t)b * NSP + nrow) * CH + o_col] = f2bf((acc[ot][r] + bqv) * qscale);
      }
    }
  }
  __syncthreads();  // all wbuf reads done before restaging

  // ---------------- K ----------------
  STAGEW(wkb);
  asm volatile("s_waitcnt vmcnt(0)" ::: "memory");
  __syncthreads();
  {
    f32x4 acc[8] = {};
#pragma unroll
    for (int kk = 0; kk < 4; ++kk)
#pragma unroll
      for (int ot = 0; ot < 8; ++ot) acc[ot] = mfma16(xfr[kk], WFRAG(ot, kk), acc[ot]);
#pragma unroll
    for (int ot = 0; ot < 8; ++ot) {
      int o_col = ot * 16 + lr;
      float bkv = bk[o_col];
#pragma unroll
      for (int r = 0; r < 4; ++r) {
        int nrow = n_base + lg * 4 + r;
        int cperm = ((((o_col >> 3) ^ (nrow & 7)) << 3)) | (o_col & 7);
        k[((size_t)b * NSP + nrow) * CH + cperm] = f2bf(acc[ot][r] + bkv);
      }
    }
  }
  __syncthreads();

  // ---------------- V (swapped operands; fragment-order store) ----------------
  STAGEW(wvb);
  asm volatile("s_waitcnt vmcnt(0)" ::: "memory");
  __syncthreads();
  {
    f32x4 acc[8] = {};
#pragma unroll
    for (int kk = 0; kk < 4; ++kk)
#pragma unroll
      for (int ot = 0; ot < 8; ++ot) acc[ot] = mfma16(WFRAG(ot, kk), xfr[kk], acc[ot]);
    // v-store fragment coords: key jj = wave*16 + lr within tile blockIdx.x
    int jj = wave * 16 + lr;
    int frv = (jj >> 5) * 4 + ((jj & 15) >> 2);  // kk2*4 + lg_v
    int ev = (lr & 3) + ((wave & 1) << 2);       // element within fragment
#pragma unroll
    for (int ot = 0; ot < 8; ++ot) {
#pragma unroll
      for (int r = 0; r < 4; ++r) {
        int c = ot * 16 + lg * 4 + r;  // v output channel
        int slot = frv ^ (c & 7);
        v[((size_t)(b * CH + c)) * NSP + blockIdx.x * 64 + slot * 8 + ev] =
            f2bf(acc[ot][r] + bv[c]);
      }
    }
  }
}

// ---------------- flash attention (no-max, KV-split=2, gl2lds double-buffer) --------
// r18 kernel unchanged (verified converged: 8 variants within +-4%; this one 81us,
// MfmaUtil 37.5). ONE vmcnt(0) + ONE barrier per iteration; pre-permuted K/V global
// layouts -> linear LDS dests + XOR-slot conflict-free ds_reads; l-sums via
// MFMA(P, ones); K(t+1) staged right after the barrier, V(t+1) after QK.
__global__ __launch_bounds__(256, 2) void attn_kernel(const u16* __restrict__ q,
                                                      const u16* __restrict__ k,
                                                      const u16* __restrict__ v,
                                                      u16* __restrict__ part0,
                                                      u16* __restrict__ part1,
                                                      float* __restrict__ lbuf) {
  __shared__ __align__(16) u16 kbuf[2][64 * 128];  // 2 x 16 KB
  __shared__ __align__(16) u16 vbuf[2][128 * 64];  // 2 x 16 KB
  int id = blockIdx.x;
  int b = id & 7;
  int qblk = (id >> 3) & 31;
  int split = id >> 8;  // 0 or 1
  int wave = threadIdx.x >> 6, lane = threadIdx.x & 63;
  int lr = lane & 15, lg = lane >> 4;
  int i_base = qblk * 128 + wave * 32;
  int t0 = split * 32, t1 = t0 + 32;

  const u16* kg = k + (size_t)b * NSP * CH;
  const u16* vg = v + (size_t)b * CH * NSP;

  // Q fragments (B-operand: q-row at lane&15), 2 q-tiles x 4 k-chunks
  bf16x8 qa[2][4];
#pragma unroll
  for (int qt = 0; qt < 2; ++qt) {
    const u16* qrow = q + ((size_t)b * NSP + i_base + qt * 16 + lr) * CH;
#pragma unroll
    for (int kk = 0; kk < 4; ++kk) qa[qt][kk] = ld_bf8(qrow + kk * 32 + lg * 8);
  }

  // staging (linear): K = 4 x 1024B (4 rows of 256B); V = 4 x 1024B (8 rows of 128B)
  auto STAGEK = [&](int t, int bi) {
    const u16* src = kg + ((size_t)(t * 64 + wave * 16)) * CH + lane * 8;
    u16* dst = &kbuf[bi][wave * 16 * 128];
#pragma unroll
    for (int g = 0; g < 4; ++g) gl2lds16(src + g * 512, dst + g * 512);
  };
  int vco = wave * 32 + (lane >> 3);
  auto STAGEV = [&](int t, int bi) {
    const u16* src = vg + t * 64 + (lane & 7) * 8;
    u16* dst = &vbuf[bi][wave * 32 * 64];
#pragma unroll
    for (int g = 0; g < 4; ++g) gl2lds16(src + (size_t)(vco + g * 8) * NSP, dst + g * 512);
  };

  STAGEK(t0, 0);
  STAGEV(t0, 0);

  // all-ones B fragment for l row-sums via MFMA
  const u32x4 ones_u = {0x3F803F80u, 0x3F803F80u, 0x3F803F80u, 0x3F803F80u};
  const bf16x8 ones = __builtin_bit_cast(bf16x8, ones_u);

  f32x4 oacc[2][8] = {};
  f32x4 lacc[2] = {};

  for (int t = t0; t < t1; ++t) {
    int cur = (t - t0) & 1;
    const u16* kb = kbuf[cur];
    const u16* vb = vbuf[cur];
    asm volatile("s_waitcnt vmcnt(0)" ::: "memory");  // my stages for tile t arrived
    __builtin_amdgcn_s_barrier();                     // all stages visible; cur^1 free
    __builtin_amdgcn_sched_barrier(0);
    if (t + 1 < t1) STAGEK(t + 1, cur ^ 1);  // K first: needed at top of next iter

    // ---- S^T = K Q^T : lane holds 16 scores for q-row lr (per qt) ----
    f32x4 s[2][4] = {};
    __builtin_amdgcn_s_setprio(1);
#pragma unroll
    for (int kk = 0; kk < 4; ++kk) {
#pragma unroll
      for (int jt = 0; jt < 4; ++jt) {
        int row = jt * 16 + lr;
        bf16x8 kf = ld_bf8(kb + row * 128 + ((((kk << 2) + lg) ^ (row & 7)) << 3));
        s[0][jt] = mfma16(kf, qa[0][kk], s[0][jt]);
        s[1][jt] = mfma16(kf, qa[1][kk], s[1][jt]);
      }
    }
    __builtin_amdgcn_s_setprio(0);
    if (t + 1 < t1) STAGEV(t + 1, cur ^ 1);  // V needed only at next iter's PV

    // ---- softmax+PV interleaved per key-half kk2; l-sums via MFMA(P, ones) ----
#pragma unroll
    for (int kk2 = 0; kk2 < 2; ++kk2) {
      u32x4 paw[2];
#pragma unroll
      for (int qt = 0; qt < 2; ++qt) {
        float p0 = fast_exp2(s[qt][2 * kk2][0]);
        float p1 = fast_exp2(s[qt][2 * kk2][1]);
        float p2 = fast_exp2(s[qt][2 * kk2][2]);
        float p3 = fast_exp2(s[qt][2 * kk2][3]);
        float p4 = fast_exp2(s[qt][2 * kk2 + 1][0]);
        float p5 = fast_exp2(s[qt][2 * kk2 + 1][1]);
        float p6 = fast_exp2(s[qt][2 * kk2 + 1][2]);
        float p7 = fast_exp2(s[qt][2 * kk2 + 1][3]);
        paw[qt][0] = cvt_pk(p0, p1);
        paw[qt][1] = cvt_pk(p2, p3);
        paw[qt][2] = cvt_pk(p4, p5);
        paw[qt][3] = cvt_pk(p6, p7);
      }
      bf16x8 pa0 = __builtin_bit_cast(bf16x8, paw[0]);
      bf16x8 pa1 = __builtin_bit_cast(bf16x8, paw[1]);
      __builtin_amdgcn_s_setprio(1);
      lacc[0] = mfma16(pa0, ones, lacc[0]);
      lacc[1] = mfma16(pa1, ones, lacc[1]);
#pragma unroll
      for (int ct = 0; ct < 8; ++ct) {
        int c = ct * 16 + lr;
        bf16x8 vf = ld_bf8(vb + c * 64 + ((((kk2 << 2) + lg) ^ (c & 7)) << 3));
        oacc[0][ct] = mfma16(pa0, vf, oacc[0][ct]);
        oacc[1][ct] = mfma16(pa1, vf, oacc[1][ct]);
      }
      __builtin_amdgcn_s_setprio(0);
    }
  }

  // ---- epilogue: write unnormalized partial (bf16) + l (f32, from lacc) ----
  u16* pdst = (split == 0) ? part0 : part1;
  float* ldst = lbuf + (size_t)split * (BATCH * NSP) + (size_t)b * NSP;
#pragma unroll
  for (int qt = 0; qt < 2; ++qt) {
#pragma unroll
    for (int r = 0; r < 4; ++r) {
      int i = i_base + qt * 16 + lg * 4 + r;
      if (lr == 0) ldst[i] = lacc[qt][r];  // row i replicated across cols; col 0 writes
      u16* row = pdst + ((size_t)b * NSP + i) * CH;
#pragma unroll
      for (int ct = 0; ct < 8; ++ct) row[ct * 16 + lr] = f2bf(oacc[qt][ct][r]);
    }
  }
}

// ---------------- output projection + residual (combines the 2 KV-split partials) ----
__global__ __launch_bounds__(256) void proj_kernel(const u16* __restrict__ p0,
                                                   const u16* __restrict__ p1,
                                                   const float* __restrict__ lbuf,
                                                   const u16* __restrict__ wob,
                                                   const float* __restrict__ bo,
                                                   const float* __restrict__ gamma,
                                                   const float* __restrict__ x,
                                                   float* __restrict__ out) {
  int b = blockIdx.y;
  int wave = threadIdx.x >> 6, lane = threadIdx.x & 63;
  int lr = lane & 15, lg = lane >> 4;
  int n_base = blockIdx.x * 64 + wave * 16;
  int nrow = n_base + lr;
  float linv = 1.f / (lbuf[(size_t)b * NSP + nrow] +
                      lbuf[(size_t)BATCH * NSP + (size_t)b * NSP + nrow]);
  const u16* r0 = p0 + ((size_t)b * NSP + nrow) * CH;
  const u16* r1 = p1 + ((size_t)b * NSP + nrow) * CH;
  f32x4 acc[8] = {};
#pragma unroll
  for (int kk = 0; kk < 4; ++kk) {
    int coff = kk * 32 + lg * 8;
    bf16x8 a = ld_bf8(r0 + coff);
    bf16x8 bb = ld_bf8(r1 + coff);
    u32 w0 = cvt_pk(((float)a[0] + (float)bb[0]) * linv, ((float)a[1] + (float)bb[1]) * linv);
    u32 w1 = cvt_pk(((float)a[2] + (float)bb[2]) * linv, ((float)a[3] + (float)bb[3]) * linv);
    u32 w2 = cvt_pk(((float)a[4] + (float)bb[4]) * linv, ((float)a[5] + (float)bb[5]) * linv);
    u32 w3 = cvt_pk(((float)a[6] + (float)bb[6]) * linv, ((float)a[7] + (float)bb[7]) * linv);
    u32x4 wv = {w0, w1, w2, w3};
    bf16x8 ofrag = __builtin_bit_cast(bf16x8, wv);
#pragma unroll
    for (int ot = 0; ot < 8; ++ot) {
      bf16x8 wf = ld_bf8(wob + (ot * 16 + lr) * CH + coff);
      acc[ot] = mfma16(wf, ofrag, acc[ot]);
    }
  }
  float g = gamma[0];
  int n_col = n_base + lr;
#pragma unroll
  for (int ot = 0; ot < 8; ++ot) {
#pragma unroll
    for (int r = 0; r < 4; ++r) {
      int o_row = ot * 16 + lg * 4 + r;
      size_t off = ((size_t)b * CH + o_row) * NSP + n_col;
      out[off] = x[off] + g * (acc[ot][r] + bo[o_row]);
    }
  }
}

extern "C" void kernel_launch(void* const* d_in, const int* in_sizes, int n_in,
                              void* d_out, int out_size, void* d_ws, size_t ws_size,
                              hipStream_t stream) {
  const float* x = (const float*)d_in[0];
  const float* gnw = (const float*)d_in[1];
  const float* gnb = (const float*)d_in[2];
  const float* wq = (const float*)d_in[3];
  const float* bq = (const float*)d_in[4];
  const float* wk = (const float*)d_in[5];
  const float* bk = (const float*)d_in[6];
  const float* wv = (const float*)d_in[7];
  const float* bv = (const float*)d_in[8];
  const float* wo = (const float*)d_in[9];
  const float* bo = (const float*)d_in[10];
  const float* gamma = (const float*)d_in[11];
  float* out = (float*)d_out;

  const size_t BUF = (size_t)BATCH * NSP * CH * sizeof(u16);  // 8 MB
  char* ws = (char*)d_ws;
  u16* wbf = (u16*)ws;             // 4 x 128x128 bf16 = 128KB
  float* stats = (float*)(ws + 131072);
  u16* xd = (u16*)(ws + 262144);   // split0 partial O
  u16* qb = (u16*)(ws + 262144 + BUF);
  u16* kb = (u16*)(ws + 262144 + 2 * BUF);
  u16* vb = (u16*)(ws + 262144 + 3 * BUF);
  float* lbuf = (float*)(ws + 262144 + 4 * BUF);  // 2 x 32768 f32 = 256KB
  const size_t need = 262144 + 4 * BUF + 262144;
  if (ws_size < need) return;
  // split1 partial: prefer extra ws space; else reuse qb (Q read only in attn prologue;
  // grid=512 at 2 blocks/CU is fully co-resident, epilogue writes land long after reads)
  u16* part1 = (ws_size >= need + BUF) ? (u16*)(ws + need) : qb;

  gn_stats_kernel<<<256, 256, 0, stream>>>(x, stats, wq, wk, wv, wo, wbf);
  qkv_kernel<<<dim3(64, 8), 256, 0, stream>>>(x, stats, gnw, gnb, wbf, wbf + 16384,
                                              wbf + 32768, bq, bk, bv, qb, kb, vb);
  attn_kernel<<<512, 256, 0, stream>>>(qb, kb, vb, xd, part1, lbuf);
  proj_kernel<<<dim3(64, 8), 256, 0, stream>>>(xd, part1, lbuf, wbf + 49152, bo, gamma,
                                               x, out);
}